// Round 2
// baseline (1466.328 us; speedup 1.0000x reference)
//
#include <hip/hip_runtime.h>
#include <math.h>

// Problem constants (from reference): B=2, T=32, H=16, W=16, D=256, NH=8, DH=32
#define NTOK 16384   // B*T*H*W
#define DD   256
#define NHD  8
#define DHD  32

// ---------------------------------------------------------------------------
// wave (64-lane) butterfly sum
__device__ __forceinline__ float wave_sum(float v) {
#pragma unroll
  for (int off = 32; off; off >>= 1) v += __shfl_xor(v, off, 64);
  return v;
}

// ---------------------------------------------------------------------------
// LayerNorm over D=256: one 64-lane wave per row, 4 rows per 256-thread block
__global__ __launch_bounds__(256) void ln_kernel(
    const float* __restrict__ x, const float* __restrict__ g,
    const float* __restrict__ b, float* __restrict__ y)
{
  const int row  = blockIdx.x * 4 + (threadIdx.x >> 6);
  const int lane = threadIdx.x & 63;
  const float4 xv = *(const float4*)&x[(size_t)row * DD + lane * 4];
  float s = xv.x + xv.y + xv.z + xv.w;
  s = wave_sum(s);
  const float mu = s * (1.0f / DD);
  const float dx = xv.x - mu, dy = xv.y - mu, dz = xv.z - mu, dw = xv.w - mu;
  float ss = dx * dx + dy * dy + dz * dz + dw * dw;
  ss = wave_sum(ss);
  const float rs = rsqrtf(ss * (1.0f / DD) + 1e-5f);
  const float4 gv = *(const float4*)&g[lane * 4];
  const float4 bv = *(const float4*)&b[lane * 4];
  float4 o;
  o.x = dx * rs * gv.x + bv.x;
  o.y = dy * rs * gv.y + bv.y;
  o.z = dz * rs * gv.z + bv.z;
  o.w = dw * rs * gv.w + bv.w;
  *(float4*)&y[(size_t)row * DD + lane * 4] = o;
}

// ---------------------------------------------------------------------------
// f32 tiled GEMM body: C[M,N] = act(A[M,K] @ Wt[K,N] + bias) (+ res)
// 256 threads, 128x128 tile, KT=16, 8x8 accum per thread.
// ACT: 0=none, 1=silu, 2=gelu(exact). RES: add res[m,n].
#define KT 16

template <int ACT, bool RES>
__device__ __forceinline__ void gemm_body(
    const float* __restrict__ A, const float* __restrict__ Wt,
    const float* __restrict__ bias, const float* __restrict__ res,
    float* __restrict__ C, int M, int N, int K, int bx, int by)
{
  __shared__ float As[KT][132];   // [k][m], padded: 132*4B = 33*16B (aligned, conflict-free)
  __shared__ float Bs[KT][128];   // [k][n]

  const int tid = threadIdx.x;
  const int m0 = by * 128;
  const int n0 = bx * 128;
  const int tx = tid & 15;        // col group (8 cols)
  const int ty = tid >> 4;        // row group (8 rows)

  // A-tile load mapping: 128 rows x 16 k; each thread: 1 row, 8 k (2 float4)
  const int la_row = tid >> 1;          // 0..127
  const int la_k   = (tid & 1) * 8;     // 0 or 8
  // B-tile load mapping: 16 k x 128 n; each thread: 1 k-row, 8 n (2 float4)
  const int lb_k = tid >> 4;            // 0..15
  const int lb_n = (tid & 15) * 8;      // 0..120

  float c[8][8];
#pragma unroll
  for (int i = 0; i < 8; i++)
#pragma unroll
    for (int j = 0; j < 8; j++) c[i][j] = 0.0f;

  for (int k0 = 0; k0 < K; k0 += KT) {
    const float4 av0 = *(const float4*)&A[(size_t)(m0 + la_row) * K + k0 + la_k];
    const float4 av1 = *(const float4*)&A[(size_t)(m0 + la_row) * K + k0 + la_k + 4];
    const float4 bv0 = *(const float4*)&Wt[(size_t)(k0 + lb_k) * N + n0 + lb_n];
    const float4 bv1 = *(const float4*)&Wt[(size_t)(k0 + lb_k) * N + n0 + lb_n + 4];
    As[la_k + 0][la_row] = av0.x;
    As[la_k + 1][la_row] = av0.y;
    As[la_k + 2][la_row] = av0.z;
    As[la_k + 3][la_row] = av0.w;
    As[la_k + 4][la_row] = av1.x;
    As[la_k + 5][la_row] = av1.y;
    As[la_k + 6][la_row] = av1.z;
    As[la_k + 7][la_row] = av1.w;
    *(float4*)&Bs[lb_k][lb_n]     = bv0;
    *(float4*)&Bs[lb_k][lb_n + 4] = bv1;
    __syncthreads();

#pragma unroll
    for (int kk = 0; kk < KT; kk++) {
      const float4 a0 = *(const float4*)&As[kk][ty * 8];
      const float4 a1 = *(const float4*)&As[kk][ty * 8 + 4];
      const float4 b0 = *(const float4*)&Bs[kk][tx * 8];
      const float4 b1 = *(const float4*)&Bs[kk][tx * 8 + 4];
      const float ar[8] = {a0.x, a0.y, a0.z, a0.w, a1.x, a1.y, a1.z, a1.w};
      const float br[8] = {b0.x, b0.y, b0.z, b0.w, b1.x, b1.y, b1.z, b1.w};
#pragma unroll
      for (int i = 0; i < 8; i++)
#pragma unroll
        for (int j = 0; j < 8; j++) c[i][j] = fmaf(ar[i], br[j], c[i][j]);
    }
    __syncthreads();
  }

  // epilogue
#pragma unroll
  for (int i = 0; i < 8; i++) {
    const int m = m0 + ty * 8 + i;
#pragma unroll
    for (int j4 = 0; j4 < 2; j4++) {
      const int n = n0 + tx * 8 + j4 * 4;
      float4 o;
      float* po = &o.x;
#pragma unroll
      for (int j = 0; j < 4; j++) {
        float v = c[i][j4 * 4 + j] + bias[n + j];
        if (ACT == 1) v = v / (1.0f + __expf(-v));                        // silu
        if (ACT == 2) v = 0.5f * v * (1.0f + erff(v * 0.70710678118654752f)); // exact gelu
        po[j] = v;
      }
      if (RES) {
        const float4 r = *(const float4*)&res[(size_t)m * N + n];
        o.x += r.x; o.y += r.y; o.z += r.z; o.w += r.w;
      }
      *(float4*)&C[(size_t)m * N + n] = o;
    }
  }
}

template <int ACT, bool RES>
__global__ __launch_bounds__(256) void gemm_kernel(
    const float* __restrict__ A, const float* __restrict__ Wt,
    const float* __restrict__ bias, const float* __restrict__ res,
    float* __restrict__ C, int M, int N, int K)
{
  gemm_body<ACT, RES>(A, Wt, bias, res, C, M, N, K, blockIdx.x, blockIdx.y);
}

// Fused Q/K/V projection: blockIdx.z selects which of the 3 GEMMs.
// Triples occupancy (768 blocks vs 256) and cuts launch count 3->1.
struct QKVArgs {
  const float *w0, *b0, *w1, *b1, *w2, *b2;
  float *c0, *c1, *c2;
};

__global__ __launch_bounds__(256) void gemm_qkv_kernel(
    const float* __restrict__ A, QKVArgs args, int M, int N, int K)
{
  const float* w = (blockIdx.z == 0) ? args.w0 : (blockIdx.z == 1) ? args.w1 : args.w2;
  const float* b = (blockIdx.z == 0) ? args.b0 : (blockIdx.z == 1) ? args.b1 : args.b2;
  float*       c = (blockIdx.z == 0) ? args.c0 : (blockIdx.z == 1) ? args.c1 : args.c2;
  gemm_body<0, false>(A, w, b, nullptr, c, M, N, K, blockIdx.x, blockIdx.y);
}

// ---------------------------------------------------------------------------
// token index for (plane batch bb, plane seq s) -> flat token in [B,T,H,W]
// PLANE 0 = HW (bb = b*T+t, s = h*W+w)       -> token = bb*256 + s
// PLANE 1 = HT (bb = b*W+w, s = t*H+h)       -> token = b*8192 + t*256 + h*16 + w
// PLANE 2 = WT (bb = b*H+h, s = t*W+w)       -> token = b*8192 + t*256 + h*16 + w
template <int PLANE>
__device__ __forceinline__ int tok_map(int bb, int s) {
  if (PLANE == 0) {
    return bb * 256 + s;
  } else if (PLANE == 1) {
    const int b = bb >> 4, w = bb & 15;
    return b * 8192 + (s >> 4) * 256 + (s & 15) * 16 + w;
  } else {
    const int b = bb >> 4, h = bb & 15;
    return b * 8192 + (s >> 4) * 256 + h * 16 + (s & 15);
  }
}

// ---------------------------------------------------------------------------
// Flash-style attention. Block = 256 threads handles one (bb, head).
// Each thread owns one query row per q-pass (S=256: 1 pass, S=512: 2 passes).
// K/V tiles of 128 rows staged in LDS (padded stride 36 -> conflict-free
// broadcast reads; 36*4B=144B keeps float4 rows 16B-aligned).
// Block-causal (block=16): key limit = ((qs>>4)+1)<<4.
template <int PLANE, bool CAUSAL>
__global__ __launch_bounds__(256) void attn_kernel(
    const float* __restrict__ Qg, const float* __restrict__ Kg,
    const float* __restrict__ Vg, float* __restrict__ Og, int S)
{
  __shared__ float Ks[128][36];
  __shared__ float Vs[128][36];
  const int bb = blockIdx.y, head = blockIdx.x, tid = threadIdx.x;
  const float scale = 0.17677669529663687f;  // 1/sqrt(32)

  for (int q0 = 0; q0 < S; q0 += 256) {
    const int qs = q0 + tid;
    const int qtok = tok_map<PLANE>(bb, qs);
    float qreg[32];
#pragma unroll
    for (int d4 = 0; d4 < 8; d4++) {
      const float4 qv = *(const float4*)&Qg[(size_t)qtok * DD + head * DHD + d4 * 4];
      qreg[d4 * 4 + 0] = qv.x; qreg[d4 * 4 + 1] = qv.y;
      qreg[d4 * 4 + 2] = qv.z; qreg[d4 * 4 + 3] = qv.w;
    }
    float o[32];
#pragma unroll
    for (int d = 0; d < 32; d++) o[d] = 0.0f;
    float mrun = -1e30f, lrun = 0.0f;

    const int lim      = CAUSAL ? (((qs >> 4) + 1) << 4) : S;        // per-thread key bound
    const int blocklim = CAUSAL ? ((((q0 + 255) >> 4) + 1) << 4) : S; // uniform bound

    for (int kt0 = 0; kt0 < blocklim; kt0 += 128) {
      __syncthreads();  // previous tile/pass readers done
      {
        const int c = (tid & 7) * 4;
#pragma unroll
        for (int rr = 0; rr < 4; rr++) {
          const int r = (tid >> 3) + rr * 32;
          const int ktok = tok_map<PLANE>(bb, kt0 + r);
          *(float4*)&Ks[r][c] = *(const float4*)&Kg[(size_t)ktok * DD + head * DHD + c];
          *(float4*)&Vs[r][c] = *(const float4*)&Vg[(size_t)ktok * DD + head * DHD + c];
        }
      }
      __syncthreads();

      const int kend = min(lim - kt0, 128);
      for (int kk = 0; kk < kend; kk++) {
        float s0 = 0, s1 = 0, s2 = 0, s3 = 0;
#pragma unroll
        for (int d4 = 0; d4 < 8; d4++) {
          const float4 kv = *(const float4*)&Ks[kk][d4 * 4];
          s0 = fmaf(qreg[d4 * 4 + 0], kv.x, s0);
          s1 = fmaf(qreg[d4 * 4 + 1], kv.y, s1);
          s2 = fmaf(qreg[d4 * 4 + 2], kv.z, s2);
          s3 = fmaf(qreg[d4 * 4 + 3], kv.w, s3);
        }
        const float sc = (s0 + s1) + (s2 + s3);
        const float sv = sc * scale;
        const float nm = fmaxf(mrun, sv);
        const float corr = __expf(mrun - nm);   // ==1 if max unchanged
        const float p = __expf(sv - nm);
        lrun = lrun * corr + p;
        mrun = nm;
#pragma unroll
        for (int d4 = 0; d4 < 8; d4++) {
          const float4 vv = *(const float4*)&Vs[kk][d4 * 4];
          o[d4 * 4 + 0] = fmaf(o[d4 * 4 + 0], corr, p * vv.x);
          o[d4 * 4 + 1] = fmaf(o[d4 * 4 + 1], corr, p * vv.y);
          o[d4 * 4 + 2] = fmaf(o[d4 * 4 + 2], corr, p * vv.z);
          o[d4 * 4 + 3] = fmaf(o[d4 * 4 + 3], corr, p * vv.w);
        }
      }
    }

    const float inv = 1.0f / lrun;
#pragma unroll
    for (int d4 = 0; d4 < 8; d4++) {
      float4 ov;
      ov.x = o[d4 * 4 + 0] * inv; ov.y = o[d4 * 4 + 1] * inv;
      ov.z = o[d4 * 4 + 2] * inv; ov.w = o[d4 * 4 + 3] * inv;
      *(float4*)&Og[(size_t)qtok * DD + head * DHD + d4 * 4] = ov;
    }
  }
}

// ---------------------------------------------------------------------------
// gate logits + softmax over 3: one thread per (token, head)
__global__ __launch_bounds__(256) void gate_kernel(
    const float* __restrict__ t, const float* __restrict__ wg2,
    const float* __restrict__ bg2, float* __restrict__ gates)
{
  const int idx = blockIdx.x * 256 + threadIdx.x;  // NTOK*8 total
  const int token = idx >> 3, head = idx & 7;
  float a0 = bg2[head * 3 + 0], a1 = bg2[head * 3 + 1], a2 = bg2[head * 3 + 2];
  const float* trow = &t[(size_t)token * DD];
  const float* wbase = &wg2[head * 3];
  for (int k4 = 0; k4 < 64; k4++) {
    const float4 tv = *(const float4*)&trow[k4 * 4];
    const float* wr = &wbase[(k4 * 4) * 24];
    a0 = fmaf(tv.x, wr[0],      a0); a1 = fmaf(tv.x, wr[1],      a1); a2 = fmaf(tv.x, wr[2],      a2);
    a0 = fmaf(tv.y, wr[24 + 0], a0); a1 = fmaf(tv.y, wr[24 + 1], a1); a2 = fmaf(tv.y, wr[24 + 2], a2);
    a0 = fmaf(tv.z, wr[48 + 0], a0); a1 = fmaf(tv.z, wr[48 + 1], a1); a2 = fmaf(tv.z, wr[48 + 2], a2);
    a0 = fmaf(tv.w, wr[72 + 0], a0); a1 = fmaf(tv.w, wr[72 + 1], a1); a2 = fmaf(tv.w, wr[72 + 2], a2);
  }
  const float mx = fmaxf(a0, fmaxf(a1, a2));
  const float e0 = __expf(a0 - mx), e1 = __expf(a1 - mx), e2 = __expf(a2 - mx);
  const float inv = 1.0f / (e0 + e1 + e2);
  float* gp = &gates[(size_t)token * 24 + head * 3];
  gp[0] = e0 * inv; gp[1] = e1 * inv; gp[2] = e2 * inv;
}

// ---------------------------------------------------------------------------
// m = g0*o_hw + g1*o_ht + g2*o_wt  (per token, head); float4 over D
__global__ __launch_bounds__(256) void combine_kernel(
    const float* __restrict__ gates, const float* __restrict__ ohw,
    const float* __restrict__ oht, const float* __restrict__ owt,
    float* __restrict__ m)
{
  const int idx = blockIdx.x * 256 + threadIdx.x;  // NTOK*64 float4s
  const int token = idx >> 6;
  const int head = (idx >> 3) & 7;
  const float* gp = &gates[(size_t)token * 24 + head * 3];
  const float g0 = gp[0], g1 = gp[1], g2 = gp[2];
  const float4 a = ((const float4*)ohw)[idx];
  const float4 b = ((const float4*)oht)[idx];
  const float4 c = ((const float4*)owt)[idx];
  float4 r;
  r.x = g0 * a.x + g1 * b.x + g2 * c.x;
  r.y = g0 * a.y + g1 * b.y + g2 * c.y;
  r.z = g0 * a.z + g1 * b.z + g2 * c.z;
  r.w = g0 * a.w + g1 * b.w + g2 * c.w;
  ((float4*)m)[idx] = r;
}

// ---------------------------------------------------------------------------
extern "C" void kernel_launch(void* const* d_in, const int* in_sizes, int n_in,
                              void* d_out, int out_size, void* d_ws, size_t ws_size,
                              hipStream_t stream)
{
  (void)in_sizes; (void)n_in; (void)out_size; (void)ws_size;
  const float* x   = (const float*)d_in[0];
  const float* g1  = (const float*)d_in[1];
  const float* b1  = (const float*)d_in[2];
  const float* wq[3] = {(const float*)d_in[3], (const float*)d_in[9],  (const float*)d_in[15]};
  const float* bq[3] = {(const float*)d_in[4], (const float*)d_in[10], (const float*)d_in[16]};
  const float* wk[3] = {(const float*)d_in[5], (const float*)d_in[11], (const float*)d_in[17]};
  const float* bk[3] = {(const float*)d_in[6], (const float*)d_in[12], (const float*)d_in[18]};
  const float* wv[3] = {(const float*)d_in[7], (const float*)d_in[13], (const float*)d_in[19]};
  const float* bv[3] = {(const float*)d_in[8], (const float*)d_in[14], (const float*)d_in[20]};
  const float* wo  = (const float*)d_in[21];
  const float* bo  = (const float*)d_in[22];
  const float* wg1 = (const float*)d_in[23];
  const float* bg1 = (const float*)d_in[24];
  const float* wg2 = (const float*)d_in[25];
  const float* bg2 = (const float*)d_in[26];
  const float* g2  = (const float*)d_in[27];
  const float* b2  = (const float*)d_in[28];
  const float* wm1 = (const float*)d_in[29];
  const float* bm1 = (const float*)d_in[30];
  const float* wm2 = (const float*)d_in[31];
  const float* bm2 = (const float*)d_in[32];

  float* ws = (float*)d_ws;
  const size_t ND = (size_t)NTOK * DD;  // 4,194,304 floats
  float* Y   = ws;            // LN output (and later LN2 output)
  float* Qb  = Y + ND;
  float* Kb  = Qb + ND;
  float* Vb  = Kb + ND;
  float* Ohw = Vb + ND;
  float* Oht = Ohw + ND;
  float* Owt = Oht + ND;
  float* Gt  = Owt + ND;               // NTOK*24
  float* X1  = Gt + (size_t)NTOK * 24;
  float* Hh  = Kb;                     // MLP hidden (NTOK*1024) aliases Kb..Oht (free by then)

  const dim3 blk(256);
  const dim3 gN256(DD / 128, NTOK / 128);        // (2, 128)
  const dim3 gQKV(DD / 128, NTOK / 128, 3);      // (2, 128, 3)
  const dim3 gN1024(1024 / 128, NTOK / 128);     // (8, 128)

  // 1. y = LN(x)
  ln_kernel<<<NTOK / 4, blk, 0, stream>>>(x, g1, b1, Y);

  // 2-4. three attention planes (fused QKV projection per plane)
  for (int p = 0; p < 3; p++) {
    QKVArgs qa;
    qa.w0 = wq[p]; qa.b0 = bq[p]; qa.c0 = Qb;
    qa.w1 = wk[p]; qa.b1 = bk[p]; qa.c1 = Kb;
    qa.w2 = wv[p]; qa.b2 = bv[p]; qa.c2 = Vb;
    gemm_qkv_kernel<<<gQKV, blk, 0, stream>>>(Y, qa, NTOK, DD, DD);
    if (p == 0)
      attn_kernel<0, false><<<dim3(NHD, 64), blk, 0, stream>>>(Qb, Kb, Vb, Ohw, 256);
    else if (p == 1)
      attn_kernel<1, true><<<dim3(NHD, 32), blk, 0, stream>>>(Qb, Kb, Vb, Oht, 512);
    else
      attn_kernel<2, true><<<dim3(NHD, 32), blk, 0, stream>>>(Qb, Kb, Vb, Owt, 512);
  }

  // 5. gate path: t = silu(y@wg1+bg1) (into Qb), gates = softmax3(t@wg2+bg2)
  gemm_kernel<1, false><<<gN256, blk, 0, stream>>>(Y, wg1, bg1, nullptr, Qb, NTOK, DD, DD);
  gate_kernel<<<NTOK * NHD / 256, blk, 0, stream>>>(Qb, wg2, bg2, Gt);

  // 6. m = gated combine (into Vb)
  combine_kernel<<<NTOK * 64 / 256, blk, 0, stream>>>(Gt, Ohw, Oht, Owt, Vb);

  // 7. x1 = x + m@wo + bo
  gemm_kernel<0, true><<<gN256, blk, 0, stream>>>(Vb, wo, bo, x, X1, NTOK, DD, DD);

  // 8. y2 = LN(x1) (into Y)
  ln_kernel<<<NTOK / 4, blk, 0, stream>>>(X1, g2, b2, Y);

  // 9. h = gelu(y2@wm1 + bm1) (into Hh = 4*ND region)
  gemm_kernel<2, false><<<gN1024, blk, 0, stream>>>(Y, wm1, bm1, nullptr, Hh, NTOK, 1024, DD);

  // 10. out = x1 + h@wm2 + bm2
  gemm_kernel<0, true><<<gN256, blk, 0, stream>>>(Hh, wm2, bm2, X1, (float*)d_out, NTOK, DD, 1024);
}

// Round 3
// 1335.127 us; speedup vs baseline: 1.0983x; 1.0983x over previous
//
#include <hip/hip_runtime.h>
#include <math.h>

// Problem constants (from reference): B=2, T=32, H=16, W=16, D=256, NH=8, DH=32
#define NTOK 16384   // B*T*H*W
#define DD   256
#define NHD  8
#define DHD  32

// ---------------------------------------------------------------------------
// wave (64-lane) butterfly sum
__device__ __forceinline__ float wave_sum(float v) {
#pragma unroll
  for (int off = 32; off; off >>= 1) v += __shfl_xor(v, off, 64);
  return v;
}

// ---------------------------------------------------------------------------
// LayerNorm over D=256: one 64-lane wave per row, 4 rows per 256-thread block
__global__ __launch_bounds__(256) void ln_kernel(
    const float* __restrict__ x, const float* __restrict__ g,
    const float* __restrict__ b, float* __restrict__ y)
{
  const int row  = blockIdx.x * 4 + (threadIdx.x >> 6);
  const int lane = threadIdx.x & 63;
  const float4 xv = *(const float4*)&x[(size_t)row * DD + lane * 4];
  float s = xv.x + xv.y + xv.z + xv.w;
  s = wave_sum(s);
  const float mu = s * (1.0f / DD);
  const float dx = xv.x - mu, dy = xv.y - mu, dz = xv.z - mu, dw = xv.w - mu;
  float ss = dx * dx + dy * dy + dz * dz + dw * dw;
  ss = wave_sum(ss);
  const float rs = rsqrtf(ss * (1.0f / DD) + 1e-5f);
  const float4 gv = *(const float4*)&g[lane * 4];
  const float4 bv = *(const float4*)&b[lane * 4];
  float4 o;
  o.x = dx * rs * gv.x + bv.x;
  o.y = dy * rs * gv.y + bv.y;
  o.z = dz * rs * gv.z + bv.z;
  o.w = dw * rs * gv.w + bv.w;
  *(float4*)&y[(size_t)row * DD + lane * 4] = o;
}

// ---------------------------------------------------------------------------
// f32 tiled GEMM body: C[M,N] = act(A[M,K] @ Wt[K,N] + bias) (+ res)
// 256 threads, 128x128 tile, KT=16, 8x8 accum per thread.
// ACT: 0=none, 1=silu, 2=gelu(exact). RES: add res[m,n].
#define KT 16

template <int ACT, bool RES>
__device__ __forceinline__ void gemm_body(
    const float* __restrict__ A, const float* __restrict__ Wt,
    const float* __restrict__ bias, const float* __restrict__ res,
    float* __restrict__ C, int M, int N, int K, int bx, int by)
{
  __shared__ float As[KT][132];   // [k][m], padded: 132*4B = 33*16B (aligned, conflict-free)
  __shared__ float Bs[KT][128];   // [k][n]

  const int tid = threadIdx.x;
  const int m0 = by * 128;
  const int n0 = bx * 128;
  const int tx = tid & 15;        // col group (8 cols)
  const int ty = tid >> 4;        // row group (8 rows)

  // A-tile load mapping: 128 rows x 16 k; each thread: 1 row, 8 k (2 float4)
  const int la_row = tid >> 1;          // 0..127
  const int la_k   = (tid & 1) * 8;     // 0 or 8
  // B-tile load mapping: 16 k x 128 n; each thread: 1 k-row, 8 n (2 float4)
  const int lb_k = tid >> 4;            // 0..15
  const int lb_n = (tid & 15) * 8;      // 0..120

  float c[8][8];
#pragma unroll
  for (int i = 0; i < 8; i++)
#pragma unroll
    for (int j = 0; j < 8; j++) c[i][j] = 0.0f;

  for (int k0 = 0; k0 < K; k0 += KT) {
    const float4 av0 = *(const float4*)&A[(size_t)(m0 + la_row) * K + k0 + la_k];
    const float4 av1 = *(const float4*)&A[(size_t)(m0 + la_row) * K + k0 + la_k + 4];
    const float4 bv0 = *(const float4*)&Wt[(size_t)(k0 + lb_k) * N + n0 + lb_n];
    const float4 bv1 = *(const float4*)&Wt[(size_t)(k0 + lb_k) * N + n0 + lb_n + 4];
    As[la_k + 0][la_row] = av0.x;
    As[la_k + 1][la_row] = av0.y;
    As[la_k + 2][la_row] = av0.z;
    As[la_k + 3][la_row] = av0.w;
    As[la_k + 4][la_row] = av1.x;
    As[la_k + 5][la_row] = av1.y;
    As[la_k + 6][la_row] = av1.z;
    As[la_k + 7][la_row] = av1.w;
    *(float4*)&Bs[lb_k][lb_n]     = bv0;
    *(float4*)&Bs[lb_k][lb_n + 4] = bv1;
    __syncthreads();

#pragma unroll
    for (int kk = 0; kk < KT; kk++) {
      const float4 a0 = *(const float4*)&As[kk][ty * 8];
      const float4 a1 = *(const float4*)&As[kk][ty * 8 + 4];
      const float4 b0 = *(const float4*)&Bs[kk][tx * 8];
      const float4 b1 = *(const float4*)&Bs[kk][tx * 8 + 4];
      const float ar[8] = {a0.x, a0.y, a0.z, a0.w, a1.x, a1.y, a1.z, a1.w};
      const float br[8] = {b0.x, b0.y, b0.z, b0.w, b1.x, b1.y, b1.z, b1.w};
#pragma unroll
      for (int i = 0; i < 8; i++)
#pragma unroll
        for (int j = 0; j < 8; j++) c[i][j] = fmaf(ar[i], br[j], c[i][j]);
    }
    __syncthreads();
  }

  // epilogue
#pragma unroll
  for (int i = 0; i < 8; i++) {
    const int m = m0 + ty * 8 + i;
#pragma unroll
    for (int j4 = 0; j4 < 2; j4++) {
      const int n = n0 + tx * 8 + j4 * 4;
      float4 o;
      float* po = &o.x;
#pragma unroll
      for (int j = 0; j < 4; j++) {
        float v = c[i][j4 * 4 + j] + bias[n + j];
        if (ACT == 1) v = v / (1.0f + __expf(-v));                        // silu
        if (ACT == 2) v = 0.5f * v * (1.0f + erff(v * 0.70710678118654752f)); // exact gelu
        po[j] = v;
      }
      if (RES) {
        const float4 r = *(const float4*)&res[(size_t)m * N + n];
        o.x += r.x; o.y += r.y; o.z += r.z; o.w += r.w;
      }
      *(float4*)&C[(size_t)m * N + n] = o;
    }
  }
}

template <int ACT, bool RES>
__global__ __launch_bounds__(256) void gemm_kernel(
    const float* __restrict__ A, const float* __restrict__ Wt,
    const float* __restrict__ bias, const float* __restrict__ res,
    float* __restrict__ C, int M, int N, int K)
{
  gemm_body<ACT, RES>(A, Wt, bias, res, C, M, N, K, blockIdx.x, blockIdx.y);
}

// Fused Q/K/V projection: blockIdx.z selects which of the 3 GEMMs.
struct QKVArgs {
  const float *w0, *b0, *w1, *b1, *w2, *b2;
  float *c0, *c1, *c2;
};

__global__ __launch_bounds__(256) void gemm_qkv_kernel(
    const float* __restrict__ A, QKVArgs args, int M, int N, int K)
{
  const float* w = (blockIdx.z == 0) ? args.w0 : (blockIdx.z == 1) ? args.w1 : args.w2;
  const float* b = (blockIdx.z == 0) ? args.b0 : (blockIdx.z == 1) ? args.b1 : args.b2;
  float*       c = (blockIdx.z == 0) ? args.c0 : (blockIdx.z == 1) ? args.c1 : args.c2;
  gemm_body<0, false>(A, w, b, nullptr, c, M, N, K, blockIdx.x, blockIdx.y);
}

// ---------------------------------------------------------------------------
// token index for (plane batch bb, plane seq s) -> flat token in [B,T,H,W]
// PLANE 0 = HW (bb = b*T+t, s = h*W+w)       -> token = bb*256 + s
// PLANE 1 = HT (bb = b*W+w, s = t*H+h)       -> token = b*8192 + t*256 + h*16 + w
// PLANE 2 = WT (bb = b*H+h, s = t*W+w)       -> token = b*8192 + t*256 + h*16 + w
template <int PLANE>
__device__ __forceinline__ int tok_map(int bb, int s) {
  if (PLANE == 0) {
    return bb * 256 + s;
  } else if (PLANE == 1) {
    const int b = bb >> 4, w = bb & 15;
    return b * 8192 + (s >> 4) * 256 + (s & 15) * 16 + w;
  } else {
    const int b = bb >> 4, h = bb & 15;
    return b * 8192 + (s >> 4) * 256 + h * 16 + (s & 15);
  }
}

// ---------------------------------------------------------------------------
// Flash attention v2: 4 lanes per query row (8 of 32 dims each).
// Block = 256 threads = 64 query rows; grid = (head, qchunk, bb) = 2048 blocks
// for every plane -> 8 blocks/CU (LDS 18.4 KB/block). QK dot reduced across
// the 4-lane quad via __shfl_xor(1|2) (DPP quad-perm, no LDS).
// Causal limits are wave-uniform: one wave = 16 query rows = one T-block of 16.
template <int PLANE, bool CAUSAL>
__global__ __launch_bounds__(256) void attn_kernel(
    const float* __restrict__ Qg, const float* __restrict__ Kg,
    const float* __restrict__ Vg, float* __restrict__ Og, int S)
{
  __shared__ float Ks[64][36];   // stride 36 floats = 144 B (16B-aligned rows)
  __shared__ float Vs[64][36];
  const int head = blockIdx.x, qc = blockIdx.y, bb = blockIdx.z;
  const int tid = threadIdx.x;
  const int qr = tid >> 2;        // 0..63 query row within chunk
  const int dq = tid & 3;         // dim quad: owns dims [dq*8, dq*8+8)
  const float scale = 0.17677669529663687f;  // 1/sqrt(32)

  const int q0 = qc * 64;
  const int qs = q0 + qr;
  const int qtok = tok_map<PLANE>(bb, qs);
  const float* qbase = &Qg[(size_t)qtok * DD + head * DHD + dq * 8];
  const float4 qv0 = *(const float4*)qbase;
  const float4 qv1 = *(const float4*)(qbase + 4);
  const float q[8] = {qv0.x, qv0.y, qv0.z, qv0.w, qv1.x, qv1.y, qv1.z, qv1.w};

  float o[8];
#pragma unroll
  for (int d = 0; d < 8; d++) o[d] = 0.0f;
  float mrun = -1e30f, lrun = 0.0f;

  // per-wave causal key bound (uniform: qs>>4 identical across the wave's 16 rows)
  const int lim      = CAUSAL ? (((qs >> 4) + 1) << 4) : S;
  const int blocklim = CAUSAL ? (q0 + 64) : S;

  // staging map: fid = rep*256+tid; row = fid>>3 (64 rows), col = (fid&7)*4
  const int st_col = (tid & 7) * 4;

  for (int kt0 = 0; kt0 < blocklim; kt0 += 64) {
    __syncthreads();
#pragma unroll
    for (int rep = 0; rep < 2; rep++) {
      const int row = rep * 32 + (tid >> 3);
      const int ktok = tok_map<PLANE>(bb, kt0 + row);
      const float* kb = &Kg[(size_t)ktok * DD + head * DHD + st_col];
      const float* vb = &Vg[(size_t)ktok * DD + head * DHD + st_col];
      *(float4*)&Ks[row][st_col] = *(const float4*)kb;
      *(float4*)&Vs[row][st_col] = *(const float4*)vb;
    }
    __syncthreads();

    if (kt0 < lim) {                      // wave-uniform branch
      const int kend = min(lim - kt0, 64);
      for (int kk = 0; kk < kend; kk++) {
        const float4 k0 = *(const float4*)&Ks[kk][dq * 8];
        const float4 k1 = *(const float4*)&Ks[kk][dq * 8 + 4];
        float s = q[0] * k0.x;
        s = fmaf(q[1], k0.y, s);
        s = fmaf(q[2], k0.z, s);
        s = fmaf(q[3], k0.w, s);
        s = fmaf(q[4], k1.x, s);
        s = fmaf(q[5], k1.y, s);
        s = fmaf(q[6], k1.z, s);
        s = fmaf(q[7], k1.w, s);
        s += __shfl_xor(s, 1, 64);        // quad reduce (DPP)
        s += __shfl_xor(s, 2, 64);
        const float sv = s * scale;
        const float nm = fmaxf(mrun, sv);
        const float corr = __expf(mrun - nm);
        const float p = __expf(sv - nm);
        lrun = lrun * corr + p;
        mrun = nm;
        const float4 v0 = *(const float4*)&Vs[kk][dq * 8];
        const float4 v1 = *(const float4*)&Vs[kk][dq * 8 + 4];
        o[0] = fmaf(o[0], corr, p * v0.x);
        o[1] = fmaf(o[1], corr, p * v0.y);
        o[2] = fmaf(o[2], corr, p * v0.z);
        o[3] = fmaf(o[3], corr, p * v0.w);
        o[4] = fmaf(o[4], corr, p * v1.x);
        o[5] = fmaf(o[5], corr, p * v1.y);
        o[6] = fmaf(o[6], corr, p * v1.z);
        o[7] = fmaf(o[7], corr, p * v1.w);
      }
    }
  }

  const float inv = 1.0f / lrun;
  float4 ov0, ov1;
  ov0.x = o[0] * inv; ov0.y = o[1] * inv; ov0.z = o[2] * inv; ov0.w = o[3] * inv;
  ov1.x = o[4] * inv; ov1.y = o[5] * inv; ov1.z = o[6] * inv; ov1.w = o[7] * inv;
  float* obase = &Og[(size_t)qtok * DD + head * DHD + dq * 8];
  *(float4*)obase = ov0;
  *(float4*)(obase + 4) = ov1;
}

// ---------------------------------------------------------------------------
// gate logits + softmax over 3: one thread per (token, head)
__global__ __launch_bounds__(256) void gate_kernel(
    const float* __restrict__ t, const float* __restrict__ wg2,
    const float* __restrict__ bg2, float* __restrict__ gates)
{
  const int idx = blockIdx.x * 256 + threadIdx.x;  // NTOK*8 total
  const int token = idx >> 3, head = idx & 7;
  float a0 = bg2[head * 3 + 0], a1 = bg2[head * 3 + 1], a2 = bg2[head * 3 + 2];
  const float* trow = &t[(size_t)token * DD];
  const float* wbase = &wg2[head * 3];
  for (int k4 = 0; k4 < 64; k4++) {
    const float4 tv = *(const float4*)&trow[k4 * 4];
    const float* wr = &wbase[(k4 * 4) * 24];
    a0 = fmaf(tv.x, wr[0],      a0); a1 = fmaf(tv.x, wr[1],      a1); a2 = fmaf(tv.x, wr[2],      a2);
    a0 = fmaf(tv.y, wr[24 + 0], a0); a1 = fmaf(tv.y, wr[24 + 1], a1); a2 = fmaf(tv.y, wr[24 + 2], a2);
    a0 = fmaf(tv.z, wr[48 + 0], a0); a1 = fmaf(tv.z, wr[48 + 1], a1); a2 = fmaf(tv.z, wr[48 + 2], a2);
    a0 = fmaf(tv.w, wr[72 + 0], a0); a1 = fmaf(tv.w, wr[72 + 1], a1); a2 = fmaf(tv.w, wr[72 + 2], a2);
  }
  const float mx = fmaxf(a0, fmaxf(a1, a2));
  const float e0 = __expf(a0 - mx), e1 = __expf(a1 - mx), e2 = __expf(a2 - mx);
  const float inv = 1.0f / (e0 + e1 + e2);
  float* gp = &gates[(size_t)token * 24 + head * 3];
  gp[0] = e0 * inv; gp[1] = e1 * inv; gp[2] = e2 * inv;
}

// ---------------------------------------------------------------------------
// m = g0*o_hw + g1*o_ht + g2*o_wt  (per token, head); float4 over D
__global__ __launch_bounds__(256) void combine_kernel(
    const float* __restrict__ gates, const float* __restrict__ ohw,
    const float* __restrict__ oht, const float* __restrict__ owt,
    float* __restrict__ m)
{
  const int idx = blockIdx.x * 256 + threadIdx.x;  // NTOK*64 float4s
  const int token = idx >> 6;
  const int head = (idx >> 3) & 7;
  const float* gp = &gates[(size_t)token * 24 + head * 3];
  const float g0 = gp[0], g1 = gp[1], g2 = gp[2];
  const float4 a = ((const float4*)ohw)[idx];
  const float4 b = ((const float4*)oht)[idx];
  const float4 c = ((const float4*)owt)[idx];
  float4 r;
  r.x = g0 * a.x + g1 * b.x + g2 * c.x;
  r.y = g0 * a.y + g1 * b.y + g2 * c.y;
  r.z = g0 * a.z + g1 * b.z + g2 * c.z;
  r.w = g0 * a.w + g1 * b.w + g2 * c.w;
  ((float4*)m)[idx] = r;
}

// ---------------------------------------------------------------------------
extern "C" void kernel_launch(void* const* d_in, const int* in_sizes, int n_in,
                              void* d_out, int out_size, void* d_ws, size_t ws_size,
                              hipStream_t stream)
{
  (void)in_sizes; (void)n_in; (void)out_size; (void)ws_size;
  const float* x   = (const float*)d_in[0];
  const float* g1  = (const float*)d_in[1];
  const float* b1  = (const float*)d_in[2];
  const float* wq[3] = {(const float*)d_in[3], (const float*)d_in[9],  (const float*)d_in[15]};
  const float* bq[3] = {(const float*)d_in[4], (const float*)d_in[10], (const float*)d_in[16]};
  const float* wk[3] = {(const float*)d_in[5], (const float*)d_in[11], (const float*)d_in[17]};
  const float* bk[3] = {(const float*)d_in[6], (const float*)d_in[12], (const float*)d_in[18]};
  const float* wv[3] = {(const float*)d_in[7], (const float*)d_in[13], (const float*)d_in[19]};
  const float* bv[3] = {(const float*)d_in[8], (const float*)d_in[14], (const float*)d_in[20]};
  const float* wo  = (const float*)d_in[21];
  const float* bo  = (const float*)d_in[22];
  const float* wg1 = (const float*)d_in[23];
  const float* bg1 = (const float*)d_in[24];
  const float* wg2 = (const float*)d_in[25];
  const float* bg2 = (const float*)d_in[26];
  const float* g2  = (const float*)d_in[27];
  const float* b2  = (const float*)d_in[28];
  const float* wm1 = (const float*)d_in[29];
  const float* bm1 = (const float*)d_in[30];
  const float* wm2 = (const float*)d_in[31];
  const float* bm2 = (const float*)d_in[32];

  float* ws = (float*)d_ws;
  const size_t ND = (size_t)NTOK * DD;  // 4,194,304 floats
  float* Y   = ws;            // LN output (and later LN2 output)
  float* Qb  = Y + ND;
  float* Kb  = Qb + ND;
  float* Vb  = Kb + ND;
  float* Ohw = Vb + ND;
  float* Oht = Ohw + ND;
  float* Owt = Oht + ND;
  float* Gt  = Owt + ND;               // NTOK*24
  float* X1  = Gt + (size_t)NTOK * 24;
  float* Hh  = Kb;                     // MLP hidden (NTOK*1024) aliases Kb..Oht (free by then)

  const dim3 blk(256);
  const dim3 gN256(DD / 128, NTOK / 128);        // (2, 128)
  const dim3 gQKV(DD / 128, NTOK / 128, 3);      // (2, 128, 3)
  const dim3 gN1024(1024 / 128, NTOK / 128);     // (8, 128)

  // 1. y = LN(x)
  ln_kernel<<<NTOK / 4, blk, 0, stream>>>(x, g1, b1, Y);

  // 2-4. three attention planes (fused QKV projection per plane)
  for (int p = 0; p < 3; p++) {
    QKVArgs qa;
    qa.w0 = wq[p]; qa.b0 = bq[p]; qa.c0 = Qb;
    qa.w1 = wk[p]; qa.b1 = bk[p]; qa.c1 = Kb;
    qa.w2 = wv[p]; qa.b2 = bv[p]; qa.c2 = Vb;
    gemm_qkv_kernel<<<gQKV, blk, 0, stream>>>(Y, qa, NTOK, DD, DD);
    if (p == 0)
      attn_kernel<0, false><<<dim3(NHD, 256 / 64, 64), blk, 0, stream>>>(Qb, Kb, Vb, Ohw, 256);
    else if (p == 1)
      attn_kernel<1, true><<<dim3(NHD, 512 / 64, 32), blk, 0, stream>>>(Qb, Kb, Vb, Oht, 512);
    else
      attn_kernel<2, true><<<dim3(NHD, 512 / 64, 32), blk, 0, stream>>>(Qb, Kb, Vb, Owt, 512);
  }

  // 5. gate path: t = silu(y@wg1+bg1) (into Qb), gates = softmax3(t@wg2+bg2)
  gemm_kernel<1, false><<<gN256, blk, 0, stream>>>(Y, wg1, bg1, nullptr, Qb, NTOK, DD, DD);
  gate_kernel<<<NTOK * NHD / 256, blk, 0, stream>>>(Qb, wg2, bg2, Gt);

  // 6. m = gated combine (into Vb)
  combine_kernel<<<NTOK * 64 / 256, blk, 0, stream>>>(Gt, Ohw, Oht, Owt, Vb);

  // 7. x1 = x + m@wo + bo
  gemm_kernel<0, true><<<gN256, blk, 0, stream>>>(Vb, wo, bo, x, X1, NTOK, DD, DD);

  // 8. y2 = LN(x1) (into Y)
  ln_kernel<<<NTOK / 4, blk, 0, stream>>>(X1, g2, b2, Y);

  // 9. h = gelu(y2@wm1 + bm1) (into Hh = 4*ND region)
  gemm_kernel<2, false><<<gN1024, blk, 0, stream>>>(Y, wm1, bm1, nullptr, Hh, NTOK, 1024, DD);

  // 10. out = x1 + h@wm2 + bm2
  gemm_kernel<0, true><<<gN256, blk, 0, stream>>>(Hh, wm2, bm2, X1, (float*)d_out, NTOK, DD, 1024);
}

// Round 4
// 1192.121 us; speedup vs baseline: 1.2300x; 1.1200x over previous
//
#include <hip/hip_runtime.h>
#include <math.h>

// Problem constants (from reference): B=2, T=32, H=16, W=16, D=256, NH=8, DH=32
#define NTOK 16384   // B*T*H*W
#define DD   256
#define NHD  8
#define DHD  32

// ---------------------------------------------------------------------------
// wave (64-lane) butterfly sum
__device__ __forceinline__ float wave_sum(float v) {
#pragma unroll
  for (int off = 32; off; off >>= 1) v += __shfl_xor(v, off, 64);
  return v;
}

// ---------------------------------------------------------------------------
// LayerNorm over D=256: one 64-lane wave per row, 4 rows per 256-thread block
__global__ __launch_bounds__(256) void ln_kernel(
    const float* __restrict__ x, const float* __restrict__ g,
    const float* __restrict__ b, float* __restrict__ y)
{
  const int row  = blockIdx.x * 4 + (threadIdx.x >> 6);
  const int lane = threadIdx.x & 63;
  const float4 xv = *(const float4*)&x[(size_t)row * DD + lane * 4];
  float s = xv.x + xv.y + xv.z + xv.w;
  s = wave_sum(s);
  const float mu = s * (1.0f / DD);
  const float dx = xv.x - mu, dy = xv.y - mu, dz = xv.z - mu, dw = xv.w - mu;
  float ss = dx * dx + dy * dy + dz * dz + dw * dw;
  ss = wave_sum(ss);
  const float rs = rsqrtf(ss * (1.0f / DD) + 1e-5f);
  const float4 gv = *(const float4*)&g[lane * 4];
  const float4 bv = *(const float4*)&b[lane * 4];
  float4 o;
  o.x = dx * rs * gv.x + bv.x;
  o.y = dy * rs * gv.y + bv.y;
  o.z = dz * rs * gv.z + bv.z;
  o.w = dw * rs * gv.w + bv.w;
  *(float4*)&y[(size_t)row * DD + lane * 4] = o;
}

// ---------------------------------------------------------------------------
// f32 tiled GEMM body: C[M,N] = act(A[M,K] @ Wt[K,N] + bias) (+ res)
// 256 threads, 128x128 tile, KT=16, 8x8 accum per thread.
// ACT: 0=none, 1=silu, 2=gelu(exact). RES: add res[m,n].
#define KT 16

template <int ACT, bool RES>
__device__ __forceinline__ void gemm_body(
    const float* __restrict__ A, const float* __restrict__ Wt,
    const float* __restrict__ bias, const float* __restrict__ res,
    float* __restrict__ C, int M, int N, int K, int bx, int by)
{
  __shared__ float As[KT][132];   // [k][m], padded: 132*4B = 33*16B (aligned, conflict-free)
  __shared__ float Bs[KT][128];   // [k][n]

  const int tid = threadIdx.x;
  const int m0 = by * 128;
  const int n0 = bx * 128;
  const int tx = tid & 15;        // col group (8 cols)
  const int ty = tid >> 4;        // row group (8 rows)

  // A-tile load mapping: 128 rows x 16 k; each thread: 1 row, 8 k (2 float4)
  const int la_row = tid >> 1;          // 0..127
  const int la_k   = (tid & 1) * 8;     // 0 or 8
  // B-tile load mapping: 16 k x 128 n; each thread: 1 k-row, 8 n (2 float4)
  const int lb_k = tid >> 4;            // 0..15
  const int lb_n = (tid & 15) * 8;      // 0..120

  float c[8][8];
#pragma unroll
  for (int i = 0; i < 8; i++)
#pragma unroll
    for (int j = 0; j < 8; j++) c[i][j] = 0.0f;

  for (int k0 = 0; k0 < K; k0 += KT) {
    const float4 av0 = *(const float4*)&A[(size_t)(m0 + la_row) * K + k0 + la_k];
    const float4 av1 = *(const float4*)&A[(size_t)(m0 + la_row) * K + k0 + la_k + 4];
    const float4 bv0 = *(const float4*)&Wt[(size_t)(k0 + lb_k) * N + n0 + lb_n];
    const float4 bv1 = *(const float4*)&Wt[(size_t)(k0 + lb_k) * N + n0 + lb_n + 4];
    As[la_k + 0][la_row] = av0.x;
    As[la_k + 1][la_row] = av0.y;
    As[la_k + 2][la_row] = av0.z;
    As[la_k + 3][la_row] = av0.w;
    As[la_k + 4][la_row] = av1.x;
    As[la_k + 5][la_row] = av1.y;
    As[la_k + 6][la_row] = av1.z;
    As[la_k + 7][la_row] = av1.w;
    *(float4*)&Bs[lb_k][lb_n]     = bv0;
    *(float4*)&Bs[lb_k][lb_n + 4] = bv1;
    __syncthreads();

#pragma unroll
    for (int kk = 0; kk < KT; kk++) {
      const float4 a0 = *(const float4*)&As[kk][ty * 8];
      const float4 a1 = *(const float4*)&As[kk][ty * 8 + 4];
      const float4 b0 = *(const float4*)&Bs[kk][tx * 8];
      const float4 b1 = *(const float4*)&Bs[kk][tx * 8 + 4];
      const float ar[8] = {a0.x, a0.y, a0.z, a0.w, a1.x, a1.y, a1.z, a1.w};
      const float br[8] = {b0.x, b0.y, b0.z, b0.w, b1.x, b1.y, b1.z, b1.w};
#pragma unroll
      for (int i = 0; i < 8; i++)
#pragma unroll
        for (int j = 0; j < 8; j++) c[i][j] = fmaf(ar[i], br[j], c[i][j]);
    }
    __syncthreads();
  }

  // epilogue
#pragma unroll
  for (int i = 0; i < 8; i++) {
    const int m = m0 + ty * 8 + i;
#pragma unroll
    for (int j4 = 0; j4 < 2; j4++) {
      const int n = n0 + tx * 8 + j4 * 4;
      float4 o;
      float* po = &o.x;
#pragma unroll
      for (int j = 0; j < 4; j++) {
        float v = c[i][j4 * 4 + j] + bias[n + j];
        if (ACT == 1) v = v / (1.0f + __expf(-v));                        // silu
        if (ACT == 2) v = 0.5f * v * (1.0f + erff(v * 0.70710678118654752f)); // exact gelu
        po[j] = v;
      }
      if (RES) {
        const float4 r = *(const float4*)&res[(size_t)m * N + n];
        o.x += r.x; o.y += r.y; o.z += r.z; o.w += r.w;
      }
      *(float4*)&C[(size_t)m * N + n] = o;
    }
  }
}

template <int ACT, bool RES>
__global__ __launch_bounds__(256) void gemm_kernel(
    const float* __restrict__ A, const float* __restrict__ Wt,
    const float* __restrict__ bias, const float* __restrict__ res,
    float* __restrict__ C, int M, int N, int K)
{
  gemm_body<ACT, RES>(A, Wt, bias, res, C, M, N, K, blockIdx.x, blockIdx.y);
}

// Fused Q/K/V projection: blockIdx.z selects which of the 3 GEMMs.
struct QKVArgs {
  const float *w0, *b0, *w1, *b1, *w2, *b2;
  float *c0, *c1, *c2;
};

__global__ __launch_bounds__(256) void gemm_qkv_kernel(
    const float* __restrict__ A, QKVArgs args, int M, int N, int K)
{
  const float* w = (blockIdx.z == 0) ? args.w0 : (blockIdx.z == 1) ? args.w1 : args.w2;
  const float* b = (blockIdx.z == 0) ? args.b0 : (blockIdx.z == 1) ? args.b1 : args.b2;
  float*       c = (blockIdx.z == 0) ? args.c0 : (blockIdx.z == 1) ? args.c1 : args.c2;
  gemm_body<0, false>(A, w, b, nullptr, c, M, N, K, blockIdx.x, blockIdx.y);
}

// ---------------------------------------------------------------------------
// token index for (plane batch bb, plane seq s) -> flat token in [B,T,H,W]
// PLANE 0 = HW (bb = b*T+t, s = h*W+w)       -> token = bb*256 + s
// PLANE 1 = HT (bb = b*W+w, s = t*H+h)       -> token = b*8192 + t*256 + h*16 + w
// PLANE 2 = WT (bb = b*H+h, s = t*W+w)       -> token = b*8192 + t*256 + h*16 + w
template <int PLANE>
__device__ __forceinline__ int tok_map(int bb, int s) {
  if (PLANE == 0) {
    return bb * 256 + s;
  } else if (PLANE == 1) {
    const int b = bb >> 4, w = bb & 15;
    return b * 8192 + (s >> 4) * 256 + (s & 15) * 16 + w;
  } else {
    const int b = bb >> 4, h = bb & 15;
    return b * 8192 + (s >> 4) * 256 + h * 16 + (s & 15);
  }
}

// ---------------------------------------------------------------------------
// Flash attention v3: tile-level two-phase softmax, no per-key serial chain.
// 4 lanes per query row (8 of 32 output dims each); 64 q-rows per 256-thread
// block; K/V tiles of 64 keys in LDS (stride 36 floats, conflict-free
// broadcast reads). Phase A: each lane computes FULL 32-dim dots for its own
// 16 keys (kk = 4g+dq) -> sreg[16], statically indexed. Phase B: one tile max
// (16 fmax + 2 quad shfl), ONE o-rescale per tile, 16 exps/lane/tile, quad
// butterfly (3 shfl / 4 keys) broadcasts p, then plain o += p*v.
// Causal (block=16): per-wave-uniform key bound; tail keys masked to -1e30
// (kend is always a multiple of 16).
template <int PLANE, bool CAUSAL>
__global__ __launch_bounds__(256) void attn_kernel(
    const float* __restrict__ Qg, const float* __restrict__ Kg,
    const float* __restrict__ Vg, float* __restrict__ Og, int S)
{
  __shared__ float Ks[64][36];   // stride 36 floats = 144 B (16B-aligned rows)
  __shared__ float Vs[64][36];
  const int head = blockIdx.x, qc = blockIdx.y, bb = blockIdx.z;
  const int tid = threadIdx.x;
  const int qr = tid >> 2;        // 0..63 query row within chunk
  const int dq = tid & 3;         // quad lane: owns output dims [dq*8, dq*8+8)
  const float scale = 0.17677669529663687f;  // 1/sqrt(32)

  const int q0 = qc * 64;
  const int qs = q0 + qr;
  const int qtok = tok_map<PLANE>(bb, qs);

  // full 32-dim q row per lane (K-dots need all dims)
  float q[32];
#pragma unroll
  for (int d4 = 0; d4 < 8; d4++) {
    const float4 qv = *(const float4*)&Qg[(size_t)qtok * DD + head * DHD + d4 * 4];
    q[d4 * 4 + 0] = qv.x; q[d4 * 4 + 1] = qv.y;
    q[d4 * 4 + 2] = qv.z; q[d4 * 4 + 3] = qv.w;
  }

  float o[8];
#pragma unroll
  for (int d = 0; d < 8; d++) o[d] = 0.0f;
  float mrun = -1e30f, lrun = 0.0f;

  // per-wave-uniform causal key bound (qs>>4 identical across a wave's 16 rows)
  const int lim      = CAUSAL ? (((qs >> 4) + 1) << 4) : S;
  const int blocklim = CAUSAL ? (q0 + 64) : S;

  const int st_col = (tid & 7) * 4;

  for (int kt0 = 0; kt0 < blocklim; kt0 += 64) {
    __syncthreads();
#pragma unroll
    for (int rep = 0; rep < 2; rep++) {
      const int row = rep * 32 + (tid >> 3);
      const int ktok = tok_map<PLANE>(bb, kt0 + row);
      *(float4*)&Ks[row][st_col] = *(const float4*)&Kg[(size_t)ktok * DD + head * DHD + st_col];
      *(float4*)&Vs[row][st_col] = *(const float4*)&Vg[(size_t)ktok * DD + head * DHD + st_col];
    }
    __syncthreads();

    if (kt0 >= lim) continue;          // wave-uniform skip (barriers above always reached)
    const int kend = CAUSAL ? min(lim - kt0, 64) : 64;  // multiple of 16, wave-uniform

    // ---- Phase A: scores for this lane's 16 keys (kk = 4g+dq), no shuffles
    float sreg[16];
    float mtile = -1e30f;
#pragma unroll
    for (int g = 0; g < 16; g++) {
      const int kk = g * 4 + dq;
      float a0 = 0, a1 = 0, a2 = 0, a3 = 0;
#pragma unroll
      for (int d4 = 0; d4 < 8; d4++) {
        const float4 kv = *(const float4*)&Ks[kk][d4 * 4];
        a0 = fmaf(q[d4 * 4 + 0], kv.x, a0);
        a1 = fmaf(q[d4 * 4 + 1], kv.y, a1);
        a2 = fmaf(q[d4 * 4 + 2], kv.z, a2);
        a3 = fmaf(q[d4 * 4 + 3], kv.w, a3);
      }
      float sv = ((a0 + a1) + (a2 + a3)) * scale;
      if (CAUSAL) sv = (kk < kend) ? sv : -1e30f;
      sreg[g] = sv;
      mtile = fmaxf(mtile, sv);
    }
    mtile = fmaxf(mtile, __shfl_xor(mtile, 1, 64));   // quad max (DPP)
    mtile = fmaxf(mtile, __shfl_xor(mtile, 2, 64));

    const float mnew = fmaxf(mrun, mtile);
    const float corr = __expf(mrun - mnew);
    mrun = mnew;
    lrun *= corr;
#pragma unroll
    for (int d = 0; d < 8; d++) o[d] *= corr;

    // ---- Phase B: p = exp(s - mnew); quad butterfly broadcast; o += p*v
    float psum = 0.0f;
#pragma unroll
    for (int g = 0; g < 16; g++) {
      const float p0 = __expf(sreg[g] - mnew);
      psum += p0;
      const float p1 = __shfl_xor(p0, 1, 64);   // key 4g + (dq^1)
      const float p2 = __shfl_xor(p0, 2, 64);   // key 4g + (dq^2)
      const float p3 = __shfl_xor(p1, 2, 64);   // key 4g + (dq^3)
      const int k0 = g * 4 + dq;
      const int k1 = g * 4 + (dq ^ 1);
      const int k2 = g * 4 + (dq ^ 2);
      const int k3 = g * 4 + (dq ^ 3);
      const float4 v00 = *(const float4*)&Vs[k0][dq * 8];
      const float4 v01 = *(const float4*)&Vs[k0][dq * 8 + 4];
      const float4 v10 = *(const float4*)&Vs[k1][dq * 8];
      const float4 v11 = *(const float4*)&Vs[k1][dq * 8 + 4];
      const float4 v20 = *(const float4*)&Vs[k2][dq * 8];
      const float4 v21 = *(const float4*)&Vs[k2][dq * 8 + 4];
      const float4 v30 = *(const float4*)&Vs[k3][dq * 8];
      const float4 v31 = *(const float4*)&Vs[k3][dq * 8 + 4];
      o[0] = fmaf(p0, v00.x, o[0]); o[1] = fmaf(p0, v00.y, o[1]);
      o[2] = fmaf(p0, v00.z, o[2]); o[3] = fmaf(p0, v00.w, o[3]);
      o[4] = fmaf(p0, v01.x, o[4]); o[5] = fmaf(p0, v01.y, o[5]);
      o[6] = fmaf(p0, v01.z, o[6]); o[7] = fmaf(p0, v01.w, o[7]);
      o[0] = fmaf(p1, v10.x, o[0]); o[1] = fmaf(p1, v10.y, o[1]);
      o[2] = fmaf(p1, v10.z, o[2]); o[3] = fmaf(p1, v10.w, o[3]);
      o[4] = fmaf(p1, v11.x, o[4]); o[5] = fmaf(p1, v11.y, o[5]);
      o[6] = fmaf(p1, v11.z, o[6]); o[7] = fmaf(p1, v11.w, o[7]);
      o[0] = fmaf(p2, v20.x, o[0]); o[1] = fmaf(p2, v20.y, o[1]);
      o[2] = fmaf(p2, v20.z, o[2]); o[3] = fmaf(p2, v20.w, o[3]);
      o[4] = fmaf(p2, v21.x, o[4]); o[5] = fmaf(p2, v21.y, o[5]);
      o[6] = fmaf(p2, v21.z, o[6]); o[7] = fmaf(p2, v21.w, o[7]);
      o[0] = fmaf(p3, v30.x, o[0]); o[1] = fmaf(p3, v30.y, o[1]);
      o[2] = fmaf(p3, v30.z, o[2]); o[3] = fmaf(p3, v30.w, o[3]);
      o[4] = fmaf(p3, v31.x, o[4]); o[5] = fmaf(p3, v31.y, o[5]);
      o[6] = fmaf(p3, v31.z, o[6]); o[7] = fmaf(p3, v31.w, o[7]);
    }
    psum += __shfl_xor(psum, 1, 64);   // quad sum of p over all 64 keys
    psum += __shfl_xor(psum, 2, 64);
    lrun += psum;
  }

  const float inv = 1.0f / lrun;
  float4 ov0, ov1;
  ov0.x = o[0] * inv; ov0.y = o[1] * inv; ov0.z = o[2] * inv; ov0.w = o[3] * inv;
  ov1.x = o[4] * inv; ov1.y = o[5] * inv; ov1.z = o[6] * inv; ov1.w = o[7] * inv;
  float* obase = &Og[(size_t)qtok * DD + head * DHD + dq * 8];
  *(float4*)obase = ov0;
  *(float4*)(obase + 4) = ov1;
}

// ---------------------------------------------------------------------------
// gate logits + softmax over 3: one thread per (token, head)
__global__ __launch_bounds__(256) void gate_kernel(
    const float* __restrict__ t, const float* __restrict__ wg2,
    const float* __restrict__ bg2, float* __restrict__ gates)
{
  const int idx = blockIdx.x * 256 + threadIdx.x;  // NTOK*8 total
  const int token = idx >> 3, head = idx & 7;
  float a0 = bg2[head * 3 + 0], a1 = bg2[head * 3 + 1], a2 = bg2[head * 3 + 2];
  const float* trow = &t[(size_t)token * DD];
  const float* wbase = &wg2[head * 3];
  for (int k4 = 0; k4 < 64; k4++) {
    const float4 tv = *(const float4*)&trow[k4 * 4];
    const float* wr = &wbase[(k4 * 4) * 24];
    a0 = fmaf(tv.x, wr[0],      a0); a1 = fmaf(tv.x, wr[1],      a1); a2 = fmaf(tv.x, wr[2],      a2);
    a0 = fmaf(tv.y, wr[24 + 0], a0); a1 = fmaf(tv.y, wr[24 + 1], a1); a2 = fmaf(tv.y, wr[24 + 2], a2);
    a0 = fmaf(tv.z, wr[48 + 0], a0); a1 = fmaf(tv.z, wr[48 + 1], a1); a2 = fmaf(tv.z, wr[48 + 2], a2);
    a0 = fmaf(tv.w, wr[72 + 0], a0); a1 = fmaf(tv.w, wr[72 + 1], a1); a2 = fmaf(tv.w, wr[72 + 2], a2);
  }
  const float mx = fmaxf(a0, fmaxf(a1, a2));
  const float e0 = __expf(a0 - mx), e1 = __expf(a1 - mx), e2 = __expf(a2 - mx);
  const float inv = 1.0f / (e0 + e1 + e2);
  float* gp = &gates[(size_t)token * 24 + head * 3];
  gp[0] = e0 * inv; gp[1] = e1 * inv; gp[2] = e2 * inv;
}

// ---------------------------------------------------------------------------
// m = g0*o_hw + g1*o_ht + g2*o_wt  (per token, head); float4 over D
__global__ __launch_bounds__(256) void combine_kernel(
    const float* __restrict__ gates, const float* __restrict__ ohw,
    const float* __restrict__ oht, const float* __restrict__ owt,
    float* __restrict__ m)
{
  const int idx = blockIdx.x * 256 + threadIdx.x;  // NTOK*64 float4s
  const int token = idx >> 6;
  const int head = (idx >> 3) & 7;
  const float* gp = &gates[(size_t)token * 24 + head * 3];
  const float g0 = gp[0], g1 = gp[1], g2 = gp[2];
  const float4 a = ((const float4*)ohw)[idx];
  const float4 b = ((const float4*)oht)[idx];
  const float4 c = ((const float4*)owt)[idx];
  float4 r;
  r.x = g0 * a.x + g1 * b.x + g2 * c.x;
  r.y = g0 * a.y + g1 * b.y + g2 * c.y;
  r.z = g0 * a.z + g1 * b.z + g2 * c.z;
  r.w = g0 * a.w + g1 * b.w + g2 * c.w;
  ((float4*)m)[idx] = r;
}

// ---------------------------------------------------------------------------
extern "C" void kernel_launch(void* const* d_in, const int* in_sizes, int n_in,
                              void* d_out, int out_size, void* d_ws, size_t ws_size,
                              hipStream_t stream)
{
  (void)in_sizes; (void)n_in; (void)out_size; (void)ws_size;
  const float* x   = (const float*)d_in[0];
  const float* g1  = (const float*)d_in[1];
  const float* b1  = (const float*)d_in[2];
  const float* wq[3] = {(const float*)d_in[3], (const float*)d_in[9],  (const float*)d_in[15]};
  const float* bq[3] = {(const float*)d_in[4], (const float*)d_in[10], (const float*)d_in[16]};
  const float* wk[3] = {(const float*)d_in[5], (const float*)d_in[11], (const float*)d_in[17]};
  const float* bk[3] = {(const float*)d_in[6], (const float*)d_in[12], (const float*)d_in[18]};
  const float* wv[3] = {(const float*)d_in[7], (const float*)d_in[13], (const float*)d_in[19]};
  const float* bv[3] = {(const float*)d_in[8], (const float*)d_in[14], (const float*)d_in[20]};
  const float* wo  = (const float*)d_in[21];
  const float* bo  = (const float*)d_in[22];
  const float* wg1 = (const float*)d_in[23];
  const float* bg1 = (const float*)d_in[24];
  const float* wg2 = (const float*)d_in[25];
  const float* bg2 = (const float*)d_in[26];
  const float* g2  = (const float*)d_in[27];
  const float* b2  = (const float*)d_in[28];
  const float* wm1 = (const float*)d_in[29];
  const float* bm1 = (const float*)d_in[30];
  const float* wm2 = (const float*)d_in[31];
  const float* bm2 = (const float*)d_in[32];

  float* ws = (float*)d_ws;
  const size_t ND = (size_t)NTOK * DD;  // 4,194,304 floats
  float* Y   = ws;            // LN output (and later LN2 output)
  float* Qb  = Y + ND;
  float* Kb  = Qb + ND;
  float* Vb  = Kb + ND;
  float* Ohw = Vb + ND;
  float* Oht = Ohw + ND;
  float* Owt = Oht + ND;
  float* Gt  = Owt + ND;               // NTOK*24
  float* X1  = Gt + (size_t)NTOK * 24;
  float* Hh  = Kb;                     // MLP hidden (NTOK*1024) aliases Kb..Oht (free by then)

  const dim3 blk(256);
  const dim3 gN256(DD / 128, NTOK / 128);        // (2, 128)
  const dim3 gQKV(DD / 128, NTOK / 128, 3);      // (2, 128, 3)
  const dim3 gN1024(1024 / 128, NTOK / 128);     // (8, 128)

  // 1. y = LN(x)
  ln_kernel<<<NTOK / 4, blk, 0, stream>>>(x, g1, b1, Y);

  // 2-4. three attention planes (fused QKV projection per plane)
  for (int p = 0; p < 3; p++) {
    QKVArgs qa;
    qa.w0 = wq[p]; qa.b0 = bq[p]; qa.c0 = Qb;
    qa.w1 = wk[p]; qa.b1 = bk[p]; qa.c1 = Kb;
    qa.w2 = wv[p]; qa.b2 = bv[p]; qa.c2 = Vb;
    gemm_qkv_kernel<<<gQKV, blk, 0, stream>>>(Y, qa, NTOK, DD, DD);
    if (p == 0)
      attn_kernel<0, false><<<dim3(NHD, 256 / 64, 64), blk, 0, stream>>>(Qb, Kb, Vb, Ohw, 256);
    else if (p == 1)
      attn_kernel<1, true><<<dim3(NHD, 512 / 64, 32), blk, 0, stream>>>(Qb, Kb, Vb, Oht, 512);
    else
      attn_kernel<2, true><<<dim3(NHD, 512 / 64, 32), blk, 0, stream>>>(Qb, Kb, Vb, Owt, 512);
  }

  // 5. gate path: t = silu(y@wg1+bg1) (into Qb), gates = softmax3(t@wg2+bg2)
  gemm_kernel<1, false><<<gN256, blk, 0, stream>>>(Y, wg1, bg1, nullptr, Qb, NTOK, DD, DD);
  gate_kernel<<<NTOK * NHD / 256, blk, 0, stream>>>(Qb, wg2, bg2, Gt);

  // 6. m = gated combine (into Vb)
  combine_kernel<<<NTOK * 64 / 256, blk, 0, stream>>>(Gt, Ohw, Oht, Owt, Vb);

  // 7. x1 = x + m@wo + bo
  gemm_kernel<0, true><<<gN256, blk, 0, stream>>>(Vb, wo, bo, x, X1, NTOK, DD, DD);

  // 8. y2 = LN(x1) (into Y)
  ln_kernel<<<NTOK / 4, blk, 0, stream>>>(X1, g2, b2, Y);

  // 9. h = gelu(y2@wm1 + bm1) (into Hh = 4*ND region)
  gemm_kernel<2, false><<<gN1024, blk, 0, stream>>>(Y, wm1, bm1, nullptr, Hh, NTOK, 1024, DD);

  // 10. out = x1 + h@wm2 + bm2
  gemm_kernel<0, true><<<gN256, blk, 0, stream>>>(Hh, wm2, bm2, X1, (float*)d_out, NTOK, DD, 1024);
}

// Round 5
// 734.657 us; speedup vs baseline: 1.9959x; 1.6227x over previous
//
#include <hip/hip_runtime.h>
#include <math.h>

// Problem constants (from reference): B=2, T=32, H=16, W=16, D=256, NH=8, DH=32
#define NTOK 16384   // B*T*H*W
#define DD   256
#define NHD  8
#define DHD  32

typedef unsigned short ushort_t;
using short8  = __attribute__((ext_vector_type(8))) short;   // 8 bf16 (4 VGPRs)
using floatx4 = __attribute__((ext_vector_type(4))) float;   // MFMA acc

// float -> bf16 (round-nearest-even)
__device__ __forceinline__ ushort_t f2bf(float f) {
  unsigned u = __float_as_uint(f);
  u = (u + 0x7FFFu + ((u >> 16) & 1u)) >> 16;
  return (ushort_t)u;
}

// ---------------------------------------------------------------------------
// wave (64-lane) butterfly sum
__device__ __forceinline__ float wave_sum(float v) {
#pragma unroll
  for (int off = 32; off; off >>= 1) v += __shfl_xor(v, off, 64);
  return v;
}

// ---------------------------------------------------------------------------
// LayerNorm over D=256 -> bf16 output (feeds MFMA GEMM A-operands only)
__global__ __launch_bounds__(256) void ln_bf_kernel(
    const float* __restrict__ x, const float* __restrict__ g,
    const float* __restrict__ b, ushort_t* __restrict__ y)
{
  const int row  = blockIdx.x * 4 + (threadIdx.x >> 6);
  const int lane = threadIdx.x & 63;
  const float4 xv = *(const float4*)&x[(size_t)row * DD + lane * 4];
  float s = xv.x + xv.y + xv.z + xv.w;
  s = wave_sum(s);
  const float mu = s * (1.0f / DD);
  const float dx = xv.x - mu, dy = xv.y - mu, dz = xv.z - mu, dw = xv.w - mu;
  float ss = dx * dx + dy * dy + dz * dz + dw * dw;
  ss = wave_sum(ss);
  const float rs = rsqrtf(ss * (1.0f / DD) + 1e-5f);
  const float4 gv = *(const float4*)&g[lane * 4];
  const float4 bv = *(const float4*)&b[lane * 4];
  ushort4 o;
  o.x = f2bf(dx * rs * gv.x + bv.x);
  o.y = f2bf(dy * rs * gv.y + bv.y);
  o.z = f2bf(dz * rs * gv.z + bv.z);
  o.w = f2bf(dw * rs * gv.w + bv.w);
  *(ushort4*)&y[(size_t)row * DD + lane * 4] = o;
}

// ---------------------------------------------------------------------------
// Weight convert+transpose: src f32 [K][N] -> dst bf16 [N][K]
struct W11 { const float* s[11]; ushort_t* d[11]; };

__global__ __launch_bounds__(256) void convw11_kernel(W11 p) {
  const int mi = blockIdx.y;
  const int idx = blockIdx.x * 256 + threadIdx.x;  // 65536 per matrix
  const int n = idx >> 8, k = idx & 255;
  p.d[mi][n * 256 + k] = f2bf(p.s[mi][k * 256 + n]);
}

template <int KK, int NN>
__global__ __launch_bounds__(256) void convw_kernel(
    const float* __restrict__ src, ushort_t* __restrict__ dst)
{
  const int idx = blockIdx.x * 256 + threadIdx.x;  // KK*NN total
  const int n = idx / KK, k = idx % KK;
  dst[n * KK + k] = f2bf(src[(size_t)k * NN + n]);
}

// ---------------------------------------------------------------------------
// bf16 MFMA GEMM: C[M,N] = act(A[M,K]_bf16 @ Wt[N,K]_bf16^T + bias) (+res)
// 256 threads = 4 waves (2x2), tile 128x128, BK=32; each wave 64x64 = 4x4
// frags of 16x16x32. LDS k-stride 40 bf16 (80 B rows -> 2-lane/bank, free).
// ACT: 0=none,1=silu,2=gelu(exact). RES adds res[m][n] f32. OBF: bf16 out.
#define LDK 40

template <int ACT, bool RES, bool OBF>
__device__ __forceinline__ void mgemm_body(
    const ushort_t* __restrict__ A, const ushort_t* __restrict__ Wt,
    const float* __restrict__ bias, const float* __restrict__ res,
    void* __restrict__ Cout, int M, int N, int K, int bx, int by)
{
  __shared__ ushort_t As[128 * LDK];
  __shared__ ushort_t Bs[128 * LDK];
  const int tid = threadIdx.x;
  const int wid = tid >> 6;
  const int lane = tid & 63;
  const int wm = (wid >> 1) * 64;   // wave row offset in tile
  const int wn = (wid & 1) * 64;    // wave col offset
  const int m0 = by * 128, n0 = bx * 128;

  const int lrow = tid >> 1;        // 0..127 staging row
  const int lk   = (tid & 1) * 16;  // 0 or 16

  const int fr = lane & 15;         // fragment row/col
  const int fk = (lane >> 4) * 8;   // k sub-offset (0,8,16,24)

  floatx4 acc[4][4] = {};

  for (int k0 = 0; k0 < K; k0 += 32) {
    const uint4 av0 = *(const uint4*)&A[(size_t)(m0 + lrow) * K + k0 + lk];
    const uint4 av1 = *(const uint4*)&A[(size_t)(m0 + lrow) * K + k0 + lk + 8];
    const uint4 bv0 = *(const uint4*)&Wt[(size_t)(n0 + lrow) * K + k0 + lk];
    const uint4 bv1 = *(const uint4*)&Wt[(size_t)(n0 + lrow) * K + k0 + lk + 8];
    __syncthreads();                 // prev-iter readers done
    *(uint4*)&As[lrow * LDK + lk]     = av0;
    *(uint4*)&As[lrow * LDK + lk + 8] = av1;
    *(uint4*)&Bs[lrow * LDK + lk]     = bv0;
    *(uint4*)&Bs[lrow * LDK + lk + 8] = bv1;
    __syncthreads();

    short8 af[4], bf[4];
#pragma unroll
    for (int f = 0; f < 4; f++) {
      af[f] = *(const short8*)&As[(wm + f * 16 + fr) * LDK + fk];
      bf[f] = *(const short8*)&Bs[(wn + f * 16 + fr) * LDK + fk];
    }
#pragma unroll
    for (int i = 0; i < 4; i++)
#pragma unroll
      for (int j = 0; j < 4; j++)
        acc[i][j] = __builtin_amdgcn_mfma_f32_16x16x32_bf16(af[i], bf[j], acc[i][j], 0, 0, 0);
  }

  // epilogue: D row = (lane>>4)*4 + r (from A frag i), col = lane&15 (from B frag j)
  const int g4 = (lane >> 4) * 4;
#pragma unroll
  for (int i = 0; i < 4; i++) {
#pragma unroll
    for (int j = 0; j < 4; j++) {
      const int col = n0 + wn + j * 16 + fr;
      const float bb = bias[col];
#pragma unroll
      for (int r = 0; r < 4; r++) {
        const int row = m0 + wm + i * 16 + g4 + r;
        float v = acc[i][j][r] + bb;
        if (ACT == 1) v = v / (1.0f + __expf(-v));
        if (ACT == 2) v = 0.5f * v * (1.0f + erff(v * 0.70710678118654752f));
        if (RES) v += res[(size_t)row * N + col];
        if (OBF) ((ushort_t*)Cout)[(size_t)row * N + col] = f2bf(v);
        else     ((float*)Cout)[(size_t)row * N + col] = v;
      }
    }
  }
}

template <int ACT, bool RES, bool OBF>
__global__ __launch_bounds__(256) void mgemm_kernel(
    const ushort_t* __restrict__ A, const ushort_t* __restrict__ Wt,
    const float* __restrict__ bias, const float* __restrict__ res,
    void* __restrict__ C, int M, int N, int K)
{
  mgemm_body<ACT, RES, OBF>(A, Wt, bias, res, C, M, N, K, blockIdx.x, blockIdx.y);
}

// Fused Q/K/V projection: blockIdx.z selects weights/bias/output (f32 out)
struct QKVArgs {
  const ushort_t *w0, *w1, *w2;
  const float *b0, *b1, *b2;
  float *c0, *c1, *c2;
};

__global__ __launch_bounds__(256) void mgemm_qkv_kernel(
    const ushort_t* __restrict__ A, QKVArgs args, int M, int N, int K)
{
  const ushort_t* w = (blockIdx.z == 0) ? args.w0 : (blockIdx.z == 1) ? args.w1 : args.w2;
  const float*    b = (blockIdx.z == 0) ? args.b0 : (blockIdx.z == 1) ? args.b1 : args.b2;
  float*          c = (blockIdx.z == 0) ? args.c0 : (blockIdx.z == 1) ? args.c1 : args.c2;
  mgemm_body<0, false, false>(A, w, b, nullptr, c, M, N, K, blockIdx.x, blockIdx.y);
}

// ---------------------------------------------------------------------------
// token index for (plane batch bb, plane seq s) -> flat token in [B,T,H,W]
template <int PLANE>
__device__ __forceinline__ int tok_map(int bb, int s) {
  if (PLANE == 0) {
    return bb * 256 + s;
  } else if (PLANE == 1) {
    const int b = bb >> 4, w = bb & 15;
    return b * 8192 + (s >> 4) * 256 + (s & 15) * 16 + w;
  } else {
    const int b = bb >> 4, h = bb & 15;
    return b * 8192 + (s >> 4) * 256 + h * 16 + (s & 15);
  }
}

// ---------------------------------------------------------------------------
// Flash attention v3 (unchanged from round 4): tile-level two-phase softmax.
template <int PLANE, bool CAUSAL>
__global__ __launch_bounds__(256) void attn_kernel(
    const float* __restrict__ Qg, const float* __restrict__ Kg,
    const float* __restrict__ Vg, float* __restrict__ Og, int S)
{
  __shared__ float Ks[64][36];
  __shared__ float Vs[64][36];
  const int head = blockIdx.x, qc = blockIdx.y, bb = blockIdx.z;
  const int tid = threadIdx.x;
  const int qr = tid >> 2;
  const int dq = tid & 3;
  const float scale = 0.17677669529663687f;

  const int q0 = qc * 64;
  const int qs = q0 + qr;
  const int qtok = tok_map<PLANE>(bb, qs);

  float q[32];
#pragma unroll
  for (int d4 = 0; d4 < 8; d4++) {
    const float4 qv = *(const float4*)&Qg[(size_t)qtok * DD + head * DHD + d4 * 4];
    q[d4 * 4 + 0] = qv.x; q[d4 * 4 + 1] = qv.y;
    q[d4 * 4 + 2] = qv.z; q[d4 * 4 + 3] = qv.w;
  }

  float o[8];
#pragma unroll
  for (int d = 0; d < 8; d++) o[d] = 0.0f;
  float mrun = -1e30f, lrun = 0.0f;

  const int lim      = CAUSAL ? (((qs >> 4) + 1) << 4) : S;
  const int blocklim = CAUSAL ? (q0 + 64) : S;
  const int st_col = (tid & 7) * 4;

  for (int kt0 = 0; kt0 < blocklim; kt0 += 64) {
    __syncthreads();
#pragma unroll
    for (int rep = 0; rep < 2; rep++) {
      const int row = rep * 32 + (tid >> 3);
      const int ktok = tok_map<PLANE>(bb, kt0 + row);
      *(float4*)&Ks[row][st_col] = *(const float4*)&Kg[(size_t)ktok * DD + head * DHD + st_col];
      *(float4*)&Vs[row][st_col] = *(const float4*)&Vg[(size_t)ktok * DD + head * DHD + st_col];
    }
    __syncthreads();

    if (kt0 >= lim) continue;
    const int kend = CAUSAL ? min(lim - kt0, 64) : 64;

    float sreg[16];
    float mtile = -1e30f;
#pragma unroll
    for (int g = 0; g < 16; g++) {
      const int kk = g * 4 + dq;
      float a0 = 0, a1 = 0, a2 = 0, a3 = 0;
#pragma unroll
      for (int d4 = 0; d4 < 8; d4++) {
        const float4 kv = *(const float4*)&Ks[kk][d4 * 4];
        a0 = fmaf(q[d4 * 4 + 0], kv.x, a0);
        a1 = fmaf(q[d4 * 4 + 1], kv.y, a1);
        a2 = fmaf(q[d4 * 4 + 2], kv.z, a2);
        a3 = fmaf(q[d4 * 4 + 3], kv.w, a3);
      }
      float sv = ((a0 + a1) + (a2 + a3)) * scale;
      if (CAUSAL) sv = (kk < kend) ? sv : -1e30f;
      sreg[g] = sv;
      mtile = fmaxf(mtile, sv);
    }
    mtile = fmaxf(mtile, __shfl_xor(mtile, 1, 64));
    mtile = fmaxf(mtile, __shfl_xor(mtile, 2, 64));

    const float mnew = fmaxf(mrun, mtile);
    const float corr = __expf(mrun - mnew);
    mrun = mnew;
    lrun *= corr;
#pragma unroll
    for (int d = 0; d < 8; d++) o[d] *= corr;

    float psum = 0.0f;
#pragma unroll
    for (int g = 0; g < 16; g++) {
      const float p0 = __expf(sreg[g] - mnew);
      psum += p0;
      const float p1 = __shfl_xor(p0, 1, 64);
      const float p2 = __shfl_xor(p0, 2, 64);
      const float p3 = __shfl_xor(p1, 2, 64);
      const int k0 = g * 4 + dq;
      const int k1 = g * 4 + (dq ^ 1);
      const int k2 = g * 4 + (dq ^ 2);
      const int k3 = g * 4 + (dq ^ 3);
      const float4 v00 = *(const float4*)&Vs[k0][dq * 8];
      const float4 v01 = *(const float4*)&Vs[k0][dq * 8 + 4];
      const float4 v10 = *(const float4*)&Vs[k1][dq * 8];
      const float4 v11 = *(const float4*)&Vs[k1][dq * 8 + 4];
      const float4 v20 = *(const float4*)&Vs[k2][dq * 8];
      const float4 v21 = *(const float4*)&Vs[k2][dq * 8 + 4];
      const float4 v30 = *(const float4*)&Vs[k3][dq * 8];
      const float4 v31 = *(const float4*)&Vs[k3][dq * 8 + 4];
      o[0] = fmaf(p0, v00.x, o[0]); o[1] = fmaf(p0, v00.y, o[1]);
      o[2] = fmaf(p0, v00.z, o[2]); o[3] = fmaf(p0, v00.w, o[3]);
      o[4] = fmaf(p0, v01.x, o[4]); o[5] = fmaf(p0, v01.y, o[5]);
      o[6] = fmaf(p0, v01.z, o[6]); o[7] = fmaf(p0, v01.w, o[7]);
      o[0] = fmaf(p1, v10.x, o[0]); o[1] = fmaf(p1, v10.y, o[1]);
      o[2] = fmaf(p1, v10.z, o[2]); o[3] = fmaf(p1, v10.w, o[3]);
      o[4] = fmaf(p1, v11.x, o[4]); o[5] = fmaf(p1, v11.y, o[5]);
      o[6] = fmaf(p1, v11.z, o[6]); o[7] = fmaf(p1, v11.w, o[7]);
      o[0] = fmaf(p2, v20.x, o[0]); o[1] = fmaf(p2, v20.y, o[1]);
      o[2] = fmaf(p2, v20.z, o[2]); o[3] = fmaf(p2, v20.w, o[3]);
      o[4] = fmaf(p2, v21.x, o[4]); o[5] = fmaf(p2, v21.y, o[5]);
      o[6] = fmaf(p2, v21.z, o[6]); o[7] = fmaf(p2, v21.w, o[7]);
      o[0] = fmaf(p3, v30.x, o[0]); o[1] = fmaf(p3, v30.y, o[1]);
      o[2] = fmaf(p3, v30.z, o[2]); o[3] = fmaf(p3, v30.w, o[3]);
      o[4] = fmaf(p3, v31.x, o[4]); o[5] = fmaf(p3, v31.y, o[5]);
      o[6] = fmaf(p3, v31.z, o[6]); o[7] = fmaf(p3, v31.w, o[7]);
    }
    psum += __shfl_xor(psum, 1, 64);
    psum += __shfl_xor(psum, 2, 64);
    lrun += psum;
  }

  const float inv = 1.0f / lrun;
  float4 ov0, ov1;
  ov0.x = o[0] * inv; ov0.y = o[1] * inv; ov0.z = o[2] * inv; ov0.w = o[3] * inv;
  ov1.x = o[4] * inv; ov1.y = o[5] * inv; ov1.z = o[6] * inv; ov1.w = o[7] * inv;
  float* obase = &Og[(size_t)qtok * DD + head * DHD + dq * 8];
  *(float4*)obase = ov0;
  *(float4*)(obase + 4) = ov1;
}

// ---------------------------------------------------------------------------
// gate logits + softmax over 3: one thread per (token, head); t is f32
__global__ __launch_bounds__(256) void gate_kernel(
    const float* __restrict__ t, const float* __restrict__ wg2,
    const float* __restrict__ bg2, float* __restrict__ gates)
{
  const int idx = blockIdx.x * 256 + threadIdx.x;
  const int token = idx >> 3, head = idx & 7;
  float a0 = bg2[head * 3 + 0], a1 = bg2[head * 3 + 1], a2 = bg2[head * 3 + 2];
  const float* trow = &t[(size_t)token * DD];
  const float* wbase = &wg2[head * 3];
  for (int k4 = 0; k4 < 64; k4++) {
    const float4 tv = *(const float4*)&trow[k4 * 4];
    const float* wr = &wbase[(k4 * 4) * 24];
    a0 = fmaf(tv.x, wr[0],      a0); a1 = fmaf(tv.x, wr[1],      a1); a2 = fmaf(tv.x, wr[2],      a2);
    a0 = fmaf(tv.y, wr[24 + 0], a0); a1 = fmaf(tv.y, wr[24 + 1], a1); a2 = fmaf(tv.y, wr[24 + 2], a2);
    a0 = fmaf(tv.z, wr[48 + 0], a0); a1 = fmaf(tv.z, wr[48 + 1], a1); a2 = fmaf(tv.z, wr[48 + 2], a2);
    a0 = fmaf(tv.w, wr[72 + 0], a0); a1 = fmaf(tv.w, wr[72 + 1], a1); a2 = fmaf(tv.w, wr[72 + 2], a2);
  }
  const float mx = fmaxf(a0, fmaxf(a1, a2));
  const float e0 = __expf(a0 - mx), e1 = __expf(a1 - mx), e2 = __expf(a2 - mx);
  const float inv = 1.0f / (e0 + e1 + e2);
  float* gp = &gates[(size_t)token * 24 + head * 3];
  gp[0] = e0 * inv; gp[1] = e1 * inv; gp[2] = e2 * inv;
}

// ---------------------------------------------------------------------------
// m = g0*o_hw + g1*o_ht + g2*o_wt -> bf16 (feeds wo MFMA GEMM)
__global__ __launch_bounds__(256) void combine_kernel(
    const float* __restrict__ gates, const float* __restrict__ ohw,
    const float* __restrict__ oht, const float* __restrict__ owt,
    ushort_t* __restrict__ m)
{
  const int idx = blockIdx.x * 256 + threadIdx.x;  // NTOK*64 groups of 4
  const int token = idx >> 6;
  const int head = (idx >> 3) & 7;
  const float* gp = &gates[(size_t)token * 24 + head * 3];
  const float g0 = gp[0], g1 = gp[1], g2 = gp[2];
  const float4 a = ((const float4*)ohw)[idx];
  const float4 b = ((const float4*)oht)[idx];
  const float4 c = ((const float4*)owt)[idx];
  ushort4 r;
  r.x = f2bf(g0 * a.x + g1 * b.x + g2 * c.x);
  r.y = f2bf(g0 * a.y + g1 * b.y + g2 * c.y);
  r.z = f2bf(g0 * a.z + g1 * b.z + g2 * c.z);
  r.w = f2bf(g0 * a.w + g1 * b.w + g2 * c.w);
  ((ushort4*)m)[idx] = r;
}

// ---------------------------------------------------------------------------
extern "C" void kernel_launch(void* const* d_in, const int* in_sizes, int n_in,
                              void* d_out, int out_size, void* d_ws, size_t ws_size,
                              hipStream_t stream)
{
  (void)in_sizes; (void)n_in; (void)out_size; (void)ws_size;
  const float* x   = (const float*)d_in[0];
  const float* g1  = (const float*)d_in[1];
  const float* b1  = (const float*)d_in[2];
  const float* wq[3] = {(const float*)d_in[3], (const float*)d_in[9],  (const float*)d_in[15]};
  const float* bq[3] = {(const float*)d_in[4], (const float*)d_in[10], (const float*)d_in[16]};
  const float* wk[3] = {(const float*)d_in[5], (const float*)d_in[11], (const float*)d_in[17]};
  const float* bk[3] = {(const float*)d_in[6], (const float*)d_in[12], (const float*)d_in[18]};
  const float* wv[3] = {(const float*)d_in[7], (const float*)d_in[13], (const float*)d_in[19]};
  const float* bv[3] = {(const float*)d_in[8], (const float*)d_in[14], (const float*)d_in[20]};
  const float* wo  = (const float*)d_in[21];
  const float* bo  = (const float*)d_in[22];
  const float* wg1 = (const float*)d_in[23];
  const float* bg1 = (const float*)d_in[24];
  const float* wg2 = (const float*)d_in[25];
  const float* bg2 = (const float*)d_in[26];
  const float* g2  = (const float*)d_in[27];
  const float* b2  = (const float*)d_in[28];
  const float* wm1 = (const float*)d_in[29];
  const float* bm1 = (const float*)d_in[30];
  const float* wm2 = (const float*)d_in[31];
  const float* bm2 = (const float*)d_in[32];

  float* ws = (float*)d_ws;
  const size_t ND = (size_t)NTOK * DD;  // 4,194,304 floats

  // workspace layout (float units)
  ushort_t* Ybf  = (ushort_t*)ws;                       // ND bf16  (ND/2 floats)
  ushort_t* Y2bf = (ushort_t*)(ws + ND / 2);            // ND bf16
  float* Qb  = ws + ND;                                 // ND f32 (later: silu t)
  float* Kb  = Qb + ND;                                 // ND f32 ┐ Hh bf16 (2·ND) aliases
  float* Vb  = Kb + ND;                                 // ND f32 ┘ after attn planes
  float* Ohw = Vb + ND;                                 // ND f32 (later: X1)
  float* Oht = Ohw + ND;
  float* Owt = Oht + ND;
  ushort_t* Mbf = (ushort_t*)(Owt + ND);                // ND bf16
  float* Gt  = Owt + ND + ND / 2;                       // NTOK*24
  float* Wreg = Gt + (size_t)NTOK * 24;                 // bf16 weights region
  ushort_t* Wbf = (ushort_t*)Wreg;
  // 11 x 65536: [0..8] = wq/wk/wv per plane, [9]=wg1, [10]=wo; then wm1, wm2
  ushort_t* wbf11[11];
  for (int i = 0; i < 11; i++) wbf11[i] = Wbf + (size_t)i * 65536;
  ushort_t* wm1bf = Wbf + (size_t)11 * 65536;
  ushort_t* wm2bf = wm1bf + 262144;

  ushort_t* Hh = (ushort_t*)Kb;   // NTOK*1024 bf16 = 2*ND float-slots (Kb+Vb)
  float* X1 = Ohw;                // aliases Ohw after combine
  float* Ts = Qb;                 // silu output (f32), aliases Qb after planes

  const dim3 blk(256);

  // 0. weight convert+transpose (bf16 [N][K])
  {
    W11 p;
    const float* srcs[11] = {wq[0], wk[0], wv[0], wq[1], wk[1], wv[1],
                             wq[2], wk[2], wv[2], wg1, wo};
    for (int i = 0; i < 11; i++) { p.s[i] = srcs[i]; p.d[i] = wbf11[i]; }
    convw11_kernel<<<dim3(256, 11), blk, 0, stream>>>(p);
    convw_kernel<256, 1024><<<1024, blk, 0, stream>>>(wm1, wm1bf);
    convw_kernel<1024, 256><<<1024, blk, 0, stream>>>(wm2, wm2bf);
  }

  // 1. y = LN(x) -> bf16
  ln_bf_kernel<<<NTOK / 4, blk, 0, stream>>>(x, g1, b1, Ybf);

  const dim3 gN256(2, 128);
  const dim3 gQKV(2, 128, 3);
  const dim3 gN1024(8, 128);

  // 2-4. three attention planes
  for (int p = 0; p < 3; p++) {
    QKVArgs qa;
    qa.w0 = wbf11[p * 3 + 0]; qa.b0 = bq[p]; qa.c0 = Qb;
    qa.w1 = wbf11[p * 3 + 1]; qa.b1 = bk[p]; qa.c1 = Kb;
    qa.w2 = wbf11[p * 3 + 2]; qa.b2 = bv[p]; qa.c2 = Vb;
    mgemm_qkv_kernel<<<gQKV, blk, 0, stream>>>(Ybf, qa, NTOK, DD, DD);
    if (p == 0)
      attn_kernel<0, false><<<dim3(NHD, 4, 64), blk, 0, stream>>>(Qb, Kb, Vb, Ohw, 256);
    else if (p == 1)
      attn_kernel<1, true><<<dim3(NHD, 8, 32), blk, 0, stream>>>(Qb, Kb, Vb, Oht, 512);
    else
      attn_kernel<2, true><<<dim3(NHD, 8, 32), blk, 0, stream>>>(Qb, Kb, Vb, Owt, 512);
  }

  // 5. gate path: t = silu(y@wg1+bg1) f32; gates = softmax3(t@wg2+bg2)
  mgemm_kernel<1, false, false><<<gN256, blk, 0, stream>>>(Ybf, wbf11[9], bg1, nullptr, Ts, NTOK, DD, DD);
  gate_kernel<<<NTOK * NHD / 256, blk, 0, stream>>>(Ts, wg2, bg2, Gt);

  // 6. m = gated combine -> bf16
  combine_kernel<<<NTOK * 64 / 256, blk, 0, stream>>>(Gt, Ohw, Oht, Owt, Mbf);

  // 7. x1 = x + m@wo + bo (f32)
  mgemm_kernel<0, true, false><<<gN256, blk, 0, stream>>>(Mbf, wbf11[10], bo, x, X1, NTOK, DD, DD);

  // 8. y2 = LN(x1) -> bf16
  ln_bf_kernel<<<NTOK / 4, blk, 0, stream>>>(X1, g2, b2, Y2bf);

  // 9. h = gelu(y2@wm1+bm1) -> bf16
  mgemm_kernel<2, false, true><<<gN1024, blk, 0, stream>>>(Y2bf, wm1bf, bm1, nullptr, Hh, NTOK, 1024, DD);

  // 10. out = x1 + h@wm2 + bm2 (f32)
  mgemm_kernel<0, true, false><<<gN256, blk, 0, stream>>>(Hh, wm2bf, bm2, X1, (float*)d_out, NTOK, DD, 1024);
}

// Round 6
// 438.789 us; speedup vs baseline: 3.3418x; 1.6743x over previous
//
#include <hip/hip_runtime.h>
#include <math.h>

// Problem constants (from reference): B=2, T=32, H=16, W=16, D=256, NH=8, DH=32
#define NTOK 16384   // B*T*H*W
#define DD   256
#define NHD  8
#define DHD  32

typedef unsigned short ushort_t;
using short8  = __attribute__((ext_vector_type(8))) short;   // 8 bf16 (4 VGPRs)
using floatx4 = __attribute__((ext_vector_type(4))) float;   // MFMA acc

// float -> bf16 (round-nearest-even)
__device__ __forceinline__ ushort_t f2bf(float f) {
  unsigned u = __float_as_uint(f);
  u = (u + 0x7FFFu + ((u >> 16) & 1u)) >> 16;
  return (ushort_t)u;
}

// ---------------------------------------------------------------------------
// wave (64-lane) butterfly sum
__device__ __forceinline__ float wave_sum(float v) {
#pragma unroll
  for (int off = 32; off; off >>= 1) v += __shfl_xor(v, off, 64);
  return v;
}

// ---------------------------------------------------------------------------
// LayerNorm over D=256 -> bf16 output (feeds MFMA GEMM A-operands only)
__global__ __launch_bounds__(256) void ln_bf_kernel(
    const float* __restrict__ x, const float* __restrict__ g,
    const float* __restrict__ b, ushort_t* __restrict__ y)
{
  const int row  = blockIdx.x * 4 + (threadIdx.x >> 6);
  const int lane = threadIdx.x & 63;
  const float4 xv = *(const float4*)&x[(size_t)row * DD + lane * 4];
  float s = xv.x + xv.y + xv.z + xv.w;
  s = wave_sum(s);
  const float mu = s * (1.0f / DD);
  const float dx = xv.x - mu, dy = xv.y - mu, dz = xv.z - mu, dw = xv.w - mu;
  float ss = dx * dx + dy * dy + dz * dz + dw * dw;
  ss = wave_sum(ss);
  const float rs = rsqrtf(ss * (1.0f / DD) + 1e-5f);
  const float4 gv = *(const float4*)&g[lane * 4];
  const float4 bv = *(const float4*)&b[lane * 4];
  ushort4 o;
  o.x = f2bf(dx * rs * gv.x + bv.x);
  o.y = f2bf(dy * rs * gv.y + bv.y);
  o.z = f2bf(dz * rs * gv.z + bv.z);
  o.w = f2bf(dw * rs * gv.w + bv.w);
  *(ushort4*)&y[(size_t)row * DD + lane * 4] = o;
}

// ---------------------------------------------------------------------------
// Weight convert+transpose: src f32 [K][N] -> dst bf16 [N][K]
struct W11 { const float* s[11]; ushort_t* d[11]; };

__global__ __launch_bounds__(256) void convw11_kernel(W11 p) {
  const int mi = blockIdx.y;
  const int idx = blockIdx.x * 256 + threadIdx.x;  // 65536 per matrix
  const int n = idx >> 8, k = idx & 255;
  p.d[mi][n * 256 + k] = f2bf(p.s[mi][k * 256 + n]);
}

template <int KK, int NN>
__global__ __launch_bounds__(256) void convw_kernel(
    const float* __restrict__ src, ushort_t* __restrict__ dst)
{
  const int idx = blockIdx.x * 256 + threadIdx.x;  // KK*NN total
  const int n = idx / KK, k = idx % KK;
  dst[n * KK + k] = f2bf(src[(size_t)k * NN + n]);
}

// ---------------------------------------------------------------------------
// bf16 MFMA GEMM: C[M,N] = act(A[M,K]_bf16 @ Wt[N,K]_bf16^T + bias) (+res)
// 256 threads = 4 waves (2x2), tile 128x128, BK=32.
#define LDK 40

template <int ACT, bool RES, bool OBF>
__device__ __forceinline__ void mgemm_body(
    const ushort_t* __restrict__ A, const ushort_t* __restrict__ Wt,
    const float* __restrict__ bias, const float* __restrict__ res,
    void* __restrict__ Cout, int M, int N, int K, int bx, int by)
{
  __shared__ ushort_t As[128 * LDK];
  __shared__ ushort_t Bs[128 * LDK];
  const int tid = threadIdx.x;
  const int wid = tid >> 6;
  const int lane = tid & 63;
  const int wm = (wid >> 1) * 64;
  const int wn = (wid & 1) * 64;
  const int m0 = by * 128, n0 = bx * 128;

  const int lrow = tid >> 1;
  const int lk   = (tid & 1) * 16;

  const int fr = lane & 15;
  const int fk = (lane >> 4) * 8;

  floatx4 acc[4][4] = {};

  for (int k0 = 0; k0 < K; k0 += 32) {
    const uint4 av0 = *(const uint4*)&A[(size_t)(m0 + lrow) * K + k0 + lk];
    const uint4 av1 = *(const uint4*)&A[(size_t)(m0 + lrow) * K + k0 + lk + 8];
    const uint4 bv0 = *(const uint4*)&Wt[(size_t)(n0 + lrow) * K + k0 + lk];
    const uint4 bv1 = *(const uint4*)&Wt[(size_t)(n0 + lrow) * K + k0 + lk + 8];
    __syncthreads();
    *(uint4*)&As[lrow * LDK + lk]     = av0;
    *(uint4*)&As[lrow * LDK + lk + 8] = av1;
    *(uint4*)&Bs[lrow * LDK + lk]     = bv0;
    *(uint4*)&Bs[lrow * LDK + lk + 8] = bv1;
    __syncthreads();

    short8 af[4], bf[4];
#pragma unroll
    for (int f = 0; f < 4; f++) {
      af[f] = *(const short8*)&As[(wm + f * 16 + fr) * LDK + fk];
      bf[f] = *(const short8*)&Bs[(wn + f * 16 + fr) * LDK + fk];
    }
#pragma unroll
    for (int i = 0; i < 4; i++)
#pragma unroll
      for (int j = 0; j < 4; j++)
        acc[i][j] = __builtin_amdgcn_mfma_f32_16x16x32_bf16(af[i], bf[j], acc[i][j], 0, 0, 0);
  }

  const int g4 = (lane >> 4) * 4;
#pragma unroll
  for (int i = 0; i < 4; i++) {
#pragma unroll
    for (int j = 0; j < 4; j++) {
      const int col = n0 + wn + j * 16 + fr;
      const float bb = bias[col];
#pragma unroll
      for (int r = 0; r < 4; r++) {
        const int row = m0 + wm + i * 16 + g4 + r;
        float v = acc[i][j][r] + bb;
        if (ACT == 1) v = v / (1.0f + __expf(-v));
        if (ACT == 2) v = 0.5f * v * (1.0f + erff(v * 0.70710678118654752f));
        if (RES) v += res[(size_t)row * N + col];
        if (OBF) ((ushort_t*)Cout)[(size_t)row * N + col] = f2bf(v);
        else     ((float*)Cout)[(size_t)row * N + col] = v;
      }
    }
  }
}

template <int ACT, bool RES, bool OBF>
__global__ __launch_bounds__(256) void mgemm_kernel(
    const ushort_t* __restrict__ A, const ushort_t* __restrict__ Wt,
    const float* __restrict__ bias, const float* __restrict__ res,
    void* __restrict__ C, int M, int N, int K)
{
  mgemm_body<ACT, RES, OBF>(A, Wt, bias, res, C, M, N, K, blockIdx.x, blockIdx.y);
}

// Fused Q/K/V projection: blockIdx.z selects weights/bias/output; bf16 out.
struct QKVArgs {
  const ushort_t *w0, *w1, *w2;
  const float *b0, *b1, *b2;
  ushort_t *c0, *c1, *c2;
};

__global__ __launch_bounds__(256) void mgemm_qkv_kernel(
    const ushort_t* __restrict__ A, QKVArgs args, int M, int N, int K)
{
  const ushort_t* w = (blockIdx.z == 0) ? args.w0 : (blockIdx.z == 1) ? args.w1 : args.w2;
  const float*    b = (blockIdx.z == 0) ? args.b0 : (blockIdx.z == 1) ? args.b1 : args.b2;
  ushort_t*       c = (blockIdx.z == 0) ? args.c0 : (blockIdx.z == 1) ? args.c1 : args.c2;
  mgemm_body<0, false, true>(A, w, b, nullptr, c, M, N, K, blockIdx.x, blockIdx.y);
}

// ---------------------------------------------------------------------------
// token index for (plane batch bb, plane seq s) -> flat token in [B,T,H,W]
template <int PLANE>
__device__ __forceinline__ int tok_map(int bb, int s) {
  if (PLANE == 0) {
    return bb * 256 + s;
  } else if (PLANE == 1) {
    const int b = bb >> 4, w = bb & 15;
    return b * 8192 + (s >> 4) * 256 + (s & 15) * 16 + w;
  } else {
    const int b = bb >> 4, h = bb & 15;
    return b * 8192 + (s >> 4) * 256 + h * 16 + (s & 15);
  }
}

// ---------------------------------------------------------------------------
// MFMA flash attention. 256 threads = 4 waves; each wave owns 16 q-rows
// (wave w = causal block q0+16w..+15, so the causal key bound is
// wave-uniform). Per 64-key tile:
//   K staged [key][dim] (stride 40 ushorts, 80B rows, 16B-aligned),
//   V staged TRANSPOSED [dim][key'] (stride 72; key' = (key+16*(dim>>3&3))&63
//     rotation -> conflict-free ds_write_b16 staging AND aligned b128 reads),
//   QK^T: 4x mfma_16x16x32_bf16 (Q frag register-resident whole kernel),
//   softmax f32 on C-layout (row=(lane>>4)*4+r, col=lane&15=key%16),
//   P -> bf16 via per-wave LDS (stride 72) to re-layout C->A-operand,
//   PV: 4x mfma into f32 acc (o0: dims 0-15, o1: dims 16-31).
// Denominator accumulates the ROUNDED bf16 p (numerator/denominator match).
template <int PLANE, bool CAUSAL>
__global__ __launch_bounds__(256) void mattn_kernel(
    const ushort_t* __restrict__ Qg, const ushort_t* __restrict__ Kg,
    const ushort_t* __restrict__ Vg, float* __restrict__ Og, int S)
{
  __shared__ ushort_t Kls[64 * 40];        // 5120 B
  __shared__ ushort_t Vtls[32 * 72];       // 4608 B
  __shared__ ushort_t Pls[4][16 * 72];     // 9216 B (per-wave P buffers)

  const int head = blockIdx.x, qc = blockIdx.y, bb = blockIdx.z;
  const int tid = threadIdx.x;
  const int wid = tid >> 6;
  const int lane = tid & 63;
  const int fr = lane & 15;
  const int hi = lane >> 4;
  const float scale = 0.17677669529663687f;  // 1/sqrt(32)

  const int q0 = qc * 64;

  // Q A-fragment: q-row = q0 + wid*16 + fr, dims hi*8 .. hi*8+7
  const int qtok_a = tok_map<PLANE>(bb, q0 + wid * 16 + fr);
  const short8 qfrag = *(const short8*)&Qg[(size_t)qtok_a * DD + head * DHD + hi * 8];

  floatx4 o0 = {}, o1 = {};
  float mrun[4] = {-3e30f, -3e30f, -3e30f, -3e30f};
  float lrun[4] = {0.f, 0.f, 0.f, 0.f};

  const int lim      = CAUSAL ? (q0 + wid * 16 + 16) : S;  // wave-uniform
  const int blocklim = CAUSAL ? (q0 + 64) : S;

  // staging map: thread -> (key row, 8-dim segment)
  const int krow = tid >> 2;          // 0..63
  const int g    = tid & 3;           // dim-group = (dim>>3)
  const int kseg = g * 8;
  const int vcol = (krow + 16 * g) & 63;  // rotated key column for Vt

  for (int kt0 = 0; kt0 < blocklim; kt0 += 64) {
    const int ktok = tok_map<PLANE>(bb, kt0 + krow);
    const uint4 kv = *(const uint4*)&Kg[(size_t)ktok * DD + head * DHD + kseg];
    const uint4 vv = *(const uint4*)&Vg[(size_t)ktok * DD + head * DHD + kseg];
    __syncthreads();                       // previous tile's readers done
    *(uint4*)&Kls[krow * 40 + kseg] = kv;
    const ushort_t* vp = (const ushort_t*)&vv;
#pragma unroll
    for (int d = 0; d < 8; d++)
      Vtls[(kseg + d) * 72 + vcol] = vp[d];
    __syncthreads();

    if (CAUSAL && kt0 >= lim) continue;    // wave-uniform skip
    const int kend = CAUSAL ? min(lim - kt0, 64) : 64;

    // ---- QK^T: S[q][key], q-rows of this wave
    floatx4 sacc[4];
#pragma unroll
    for (int j = 0; j < 4; j++) {
      floatx4 z = {};
      const short8 kf = *(const short8*)&Kls[(j * 16 + fr) * 40 + hi * 8];
      sacc[j] = __builtin_amdgcn_mfma_f32_16x16x32_bf16(qfrag, kf, z, 0, 0, 0);
    }

    // ---- scale + causal mask + tile row-max
    float sc[4][4];
    float mt[4] = {-3e30f, -3e30f, -3e30f, -3e30f};
#pragma unroll
    for (int j = 0; j < 4; j++) {
      const bool valid = !CAUSAL || (j * 16 + fr) < kend;
#pragma unroll
      for (int r = 0; r < 4; r++) {
        const float sv = valid ? sacc[j][r] * scale : -3e30f;
        sc[j][r] = sv;
        mt[r] = fmaxf(mt[r], sv);
      }
    }
#pragma unroll
    for (int r = 0; r < 4; r++) {          // 16-lane butterfly (same hi-group)
      mt[r] = fmaxf(mt[r], __shfl_xor(mt[r], 1, 64));
      mt[r] = fmaxf(mt[r], __shfl_xor(mt[r], 2, 64));
      mt[r] = fmaxf(mt[r], __shfl_xor(mt[r], 4, 64));
      mt[r] = fmaxf(mt[r], __shfl_xor(mt[r], 8, 64));
    }

    float corr[4], psum[4];
#pragma unroll
    for (int r = 0; r < 4; r++) {
      const float mnew = fmaxf(mrun[r], mt[r]);
      corr[r] = __expf(mrun[r] - mnew);
      mrun[r] = mnew;
      psum[r] = 0.f;
    }

    // ---- P = exp(s-m) -> bf16 -> Pls; psum from rounded values
#pragma unroll
    for (int j = 0; j < 4; j++) {
#pragma unroll
      for (int r = 0; r < 4; r++) {
        const float p = __expf(sc[j][r] - mrun[r]);
        const ushort_t pb = f2bf(p);
        psum[r] += __uint_as_float((unsigned)pb << 16);
        Pls[wid][(hi * 4 + r) * 72 + j * 16 + fr] = pb;
      }
    }
#pragma unroll
    for (int r = 0; r < 4; r++) {
      psum[r] += __shfl_xor(psum[r], 1, 64);
      psum[r] += __shfl_xor(psum[r], 2, 64);
      psum[r] += __shfl_xor(psum[r], 4, 64);
      psum[r] += __shfl_xor(psum[r], 8, 64);
      lrun[r] = lrun[r] * corr[r] + psum[r];
      o0[r] *= corr[r];
      o1[r] *= corr[r];
    }

    // ---- PV: O[q][dim] += P[q][key] * V[key][dim]
    const int g0c = (fr >> 3) & 3;          // (dim0>>3)&3, dim0 = fr
    const int g1c = (2 + (fr >> 3)) & 3;    // dim1 = 16+fr
#pragma unroll
    for (int kh = 0; kh < 2; kh++) {
      const short8 pa = *(const short8*)&Pls[wid][fr * 72 + kh * 32 + hi * 8];
      const int c0 = (hi * 8 + kh * 32 + 16 * g0c) & 63;
      const int c1 = (hi * 8 + kh * 32 + 16 * g1c) & 63;
      const short8 vb0 = *(const short8*)&Vtls[fr * 72 + c0];
      const short8 vb1 = *(const short8*)&Vtls[(16 + fr) * 72 + c1];
      o0 = __builtin_amdgcn_mfma_f32_16x16x32_bf16(pa, vb0, o0, 0, 0, 0);
      o1 = __builtin_amdgcn_mfma_f32_16x16x32_bf16(pa, vb1, o1, 0, 0, 0);
    }
  }

  // ---- epilogue: normalize + store f32
#pragma unroll
  for (int r = 0; r < 4; r++) {
    const float inv = 1.0f / lrun[r];
    const int otok = tok_map<PLANE>(bb, q0 + wid * 16 + hi * 4 + r);
    float* ob = &Og[(size_t)otok * DD + head * DHD];
    ob[fr] = o0[r] * inv;
    ob[16 + fr] = o1[r] * inv;
  }
}

// ---------------------------------------------------------------------------
// gate logits + softmax over 3: one thread per (token, head); t is f32
__global__ __launch_bounds__(256) void gate_kernel(
    const float* __restrict__ t, const float* __restrict__ wg2,
    const float* __restrict__ bg2, float* __restrict__ gates)
{
  const int idx = blockIdx.x * 256 + threadIdx.x;
  const int token = idx >> 3, head = idx & 7;
  float a0 = bg2[head * 3 + 0], a1 = bg2[head * 3 + 1], a2 = bg2[head * 3 + 2];
  const float* trow = &t[(size_t)token * DD];
  const float* wbase = &wg2[head * 3];
  for (int k4 = 0; k4 < 64; k4++) {
    const float4 tv = *(const float4*)&trow[k4 * 4];
    const float* wr = &wbase[(k4 * 4) * 24];
    a0 = fmaf(tv.x, wr[0],      a0); a1 = fmaf(tv.x, wr[1],      a1); a2 = fmaf(tv.x, wr[2],      a2);
    a0 = fmaf(tv.y, wr[24 + 0], a0); a1 = fmaf(tv.y, wr[24 + 1], a1); a2 = fmaf(tv.y, wr[24 + 2], a2);
    a0 = fmaf(tv.z, wr[48 + 0], a0); a1 = fmaf(tv.z, wr[48 + 1], a1); a2 = fmaf(tv.z, wr[48 + 2], a2);
    a0 = fmaf(tv.w, wr[72 + 0], a0); a1 = fmaf(tv.w, wr[72 + 1], a1); a2 = fmaf(tv.w, wr[72 + 2], a2);
  }
  const float mx = fmaxf(a0, fmaxf(a1, a2));
  const float e0 = __expf(a0 - mx), e1 = __expf(a1 - mx), e2 = __expf(a2 - mx);
  const float inv = 1.0f / (e0 + e1 + e2);
  float* gp = &gates[(size_t)token * 24 + head * 3];
  gp[0] = e0 * inv; gp[1] = e1 * inv; gp[2] = e2 * inv;
}

// ---------------------------------------------------------------------------
// m = g0*o_hw + g1*o_ht + g2*o_wt -> bf16 (feeds wo MFMA GEMM)
__global__ __launch_bounds__(256) void combine_kernel(
    const float* __restrict__ gates, const float* __restrict__ ohw,
    const float* __restrict__ oht, const float* __restrict__ owt,
    ushort_t* __restrict__ m)
{
  const int idx = blockIdx.x * 256 + threadIdx.x;  // NTOK*64 groups of 4
  const int token = idx >> 6;
  const int head = (idx >> 3) & 7;
  const float* gp = &gates[(size_t)token * 24 + head * 3];
  const float g0 = gp[0], g1 = gp[1], g2 = gp[2];
  const float4 a = ((const float4*)ohw)[idx];
  const float4 b = ((const float4*)oht)[idx];
  const float4 c = ((const float4*)owt)[idx];
  ushort4 r;
  r.x = f2bf(g0 * a.x + g1 * b.x + g2 * c.x);
  r.y = f2bf(g0 * a.y + g1 * b.y + g2 * c.y);
  r.z = f2bf(g0 * a.z + g1 * b.z + g2 * c.z);
  r.w = f2bf(g0 * a.w + g1 * b.w + g2 * c.w);
  ((ushort4*)m)[idx] = r;
}

// ---------------------------------------------------------------------------
extern "C" void kernel_launch(void* const* d_in, const int* in_sizes, int n_in,
                              void* d_out, int out_size, void* d_ws, size_t ws_size,
                              hipStream_t stream)
{
  (void)in_sizes; (void)n_in; (void)out_size; (void)ws_size;
  const float* x   = (const float*)d_in[0];
  const float* g1  = (const float*)d_in[1];
  const float* b1  = (const float*)d_in[2];
  const float* wq[3] = {(const float*)d_in[3], (const float*)d_in[9],  (const float*)d_in[15]};
  const float* bq[3] = {(const float*)d_in[4], (const float*)d_in[10], (const float*)d_in[16]};
  const float* wk[3] = {(const float*)d_in[5], (const float*)d_in[11], (const float*)d_in[17]};
  const float* bk[3] = {(const float*)d_in[6], (const float*)d_in[12], (const float*)d_in[18]};
  const float* wv[3] = {(const float*)d_in[7], (const float*)d_in[13], (const float*)d_in[19]};
  const float* bv[3] = {(const float*)d_in[8], (const float*)d_in[14], (const float*)d_in[20]};
  const float* wo  = (const float*)d_in[21];
  const float* bo  = (const float*)d_in[22];
  const float* wg1 = (const float*)d_in[23];
  const float* bg1 = (const float*)d_in[24];
  const float* wg2 = (const float*)d_in[25];
  const float* bg2 = (const float*)d_in[26];
  const float* g2  = (const float*)d_in[27];
  const float* b2  = (const float*)d_in[28];
  const float* wm1 = (const float*)d_in[29];
  const float* bm1 = (const float*)d_in[30];
  const float* wm2 = (const float*)d_in[31];
  const float* bm2 = (const float*)d_in[32];

  float* ws = (float*)d_ws;
  const size_t ND = (size_t)NTOK * DD;  // 4,194,304 floats

  // workspace layout (float-slot units; same offsets as round 5)
  ushort_t* Ybf  = (ushort_t*)ws;                       // ND bf16
  ushort_t* Y2bf = (ushort_t*)(ws + ND / 2);            // ND bf16
  float* Qb  = ws + ND;                                 // region: ND f32 slots
  float* Kb  = Qb + ND;
  float* Vb  = Kb + ND;
  float* Ohw = Vb + ND;                                 // f32 (later X1)
  float* Oht = Ohw + ND;
  float* Owt = Oht + ND;
  ushort_t* Mbf = (ushort_t*)(Owt + ND);                // ND bf16
  float* Gt  = Owt + ND + ND / 2;                       // NTOK*24
  ushort_t* Wbf = (ushort_t*)(Gt + (size_t)NTOK * 24);
  ushort_t* wbf11[11];
  for (int i = 0; i < 11; i++) wbf11[i] = Wbf + (size_t)i * 65536;
  ushort_t* wm1bf = Wbf + (size_t)11 * 65536;
  ushort_t* wm2bf = wm1bf + 262144;

  // bf16 views of Q/K/V regions (half-used)
  ushort_t* Qbf = (ushort_t*)Qb;
  ushort_t* Kbf = (ushort_t*)Kb;
  ushort_t* Vbf = (ushort_t*)Vb;

  ushort_t* Hh = (ushort_t*)Kb;   // MLP hidden bf16: NTOK*1024 ushorts (Kb+Vb)
  float* X1 = Ohw;
  float* Ts = Qb;                 // silu output f32 (full Qb region)

  const dim3 blk(256);

  // 0. weight convert+transpose (bf16 [N][K])
  {
    W11 p;
    const float* srcs[11] = {wq[0], wk[0], wv[0], wq[1], wk[1], wv[1],
                             wq[2], wk[2], wv[2], wg1, wo};
    for (int i = 0; i < 11; i++) { p.s[i] = srcs[i]; p.d[i] = wbf11[i]; }
    convw11_kernel<<<dim3(256, 11), blk, 0, stream>>>(p);
    convw_kernel<256, 1024><<<1024, blk, 0, stream>>>(wm1, wm1bf);
    convw_kernel<1024, 256><<<1024, blk, 0, stream>>>(wm2, wm2bf);
  }

  // 1. y = LN(x) -> bf16
  ln_bf_kernel<<<NTOK / 4, blk, 0, stream>>>(x, g1, b1, Ybf);

  const dim3 gN256(2, 128);
  const dim3 gQKV(2, 128, 3);
  const dim3 gN1024(8, 128);

  // 2-4. three attention planes (QKV -> bf16; MFMA attention)
  for (int p = 0; p < 3; p++) {
    QKVArgs qa;
    qa.w0 = wbf11[p * 3 + 0]; qa.b0 = bq[p]; qa.c0 = Qbf;
    qa.w1 = wbf11[p * 3 + 1]; qa.b1 = bk[p]; qa.c1 = Kbf;
    qa.w2 = wbf11[p * 3 + 2]; qa.b2 = bv[p]; qa.c2 = Vbf;
    mgemm_qkv_kernel<<<gQKV, blk, 0, stream>>>(Ybf, qa, NTOK, DD, DD);
    if (p == 0)
      mattn_kernel<0, false><<<dim3(NHD, 4, 64), blk, 0, stream>>>(Qbf, Kbf, Vbf, Ohw, 256);
    else if (p == 1)
      mattn_kernel<1, true><<<dim3(NHD, 8, 32), blk, 0, stream>>>(Qbf, Kbf, Vbf, Oht, 512);
    else
      mattn_kernel<2, true><<<dim3(NHD, 8, 32), blk, 0, stream>>>(Qbf, Kbf, Vbf, Owt, 512);
  }

  // 5. gate path: t = silu(y@wg1+bg1) f32; gates = softmax3(t@wg2+bg2)
  mgemm_kernel<1, false, false><<<gN256, blk, 0, stream>>>(Ybf, wbf11[9], bg1, nullptr, Ts, NTOK, DD, DD);
  gate_kernel<<<NTOK * NHD / 256, blk, 0, stream>>>(Ts, wg2, bg2, Gt);

  // 6. m = gated combine -> bf16
  combine_kernel<<<NTOK * 64 / 256, blk, 0, stream>>>(Gt, Ohw, Oht, Owt, Mbf);

  // 7. x1 = x + m@wo + bo (f32)
  mgemm_kernel<0, true, false><<<gN256, blk, 0, stream>>>(Mbf, wbf11[10], bo, x, X1, NTOK, DD, DD);

  // 8. y2 = LN(x1) -> bf16
  ln_bf_kernel<<<NTOK / 4, blk, 0, stream>>>(X1, g2, b2, Y2bf);

  // 9. h = gelu(y2@wm1+bm1) -> bf16
  mgemm_kernel<2, false, true><<<gN1024, blk, 0, stream>>>(Y2bf, wm1bf, bm1, nullptr, Hh, NTOK, 1024, DD);

  // 10. out = x1 + h@wm2 + bm2 (f32)
  mgemm_kernel<0, true, false><<<gN256, blk, 0, stream>>>(Hh, wm2bf, bm2, X1, (float*)d_out, NTOK, DD, 1024);
}

// Round 7
// 386.867 us; speedup vs baseline: 3.7903x; 1.1342x over previous
//
#include <hip/hip_runtime.h>
#include <math.h>

// Problem constants: B=2, T=32, H=16, W=16, D=256, NH=8, DH=32
#define NTOK 16384
#define DD   256
#define NHD  8
#define DHD  32

typedef unsigned short ushort_t;
using short8  = __attribute__((ext_vector_type(8))) short;
using floatx4 = __attribute__((ext_vector_type(4))) float;

__device__ __forceinline__ ushort_t f2bf(float f) {
  unsigned u = __float_as_uint(f);
  u = (u + 0x7FFFu + ((u >> 16) & 1u)) >> 16;
  return (ushort_t)u;
}

__device__ __forceinline__ float wave_sum(float v) {
#pragma unroll
  for (int off = 32; off; off >>= 1) v += __shfl_xor(v, off, 64);
  return v;
}

// ---------------------------------------------------------------------------
// LayerNorm over D=256 -> bf16
__global__ __launch_bounds__(256) void ln_bf_kernel(
    const float* __restrict__ x, const float* __restrict__ g,
    const float* __restrict__ b, ushort_t* __restrict__ y)
{
  const int row  = blockIdx.x * 4 + (threadIdx.x >> 6);
  const int lane = threadIdx.x & 63;
  const float4 xv = *(const float4*)&x[(size_t)row * DD + lane * 4];
  float s = xv.x + xv.y + xv.z + xv.w;
  s = wave_sum(s);
  const float mu = s * (1.0f / DD);
  const float dx = xv.x - mu, dy = xv.y - mu, dz = xv.z - mu, dw = xv.w - mu;
  float ss = dx * dx + dy * dy + dz * dz + dw * dw;
  ss = wave_sum(ss);
  const float rs = rsqrtf(ss * (1.0f / DD) + 1e-5f);
  const float4 gv = *(const float4*)&g[lane * 4];
  const float4 bv = *(const float4*)&b[lane * 4];
  ushort4 o;
  o.x = f2bf(dx * rs * gv.x + bv.x);
  o.y = f2bf(dy * rs * gv.y + bv.y);
  o.z = f2bf(dz * rs * gv.z + bv.z);
  o.w = f2bf(dw * rs * gv.w + bv.w);
  *(ushort4*)&y[(size_t)row * DD + lane * 4] = o;
}

// ---------------------------------------------------------------------------
// Weight convert+transpose: f32 [K][N] -> bf16 [N][K]
struct W11 { const float* s[11]; ushort_t* d[11]; };

__global__ __launch_bounds__(256) void convw11_kernel(W11 p) {
  const int mi = blockIdx.y;
  const int idx = blockIdx.x * 256 + threadIdx.x;
  const int n = idx >> 8, k = idx & 255;
  p.d[mi][n * 256 + k] = f2bf(p.s[mi][k * 256 + n]);
}

template <int KK, int NN>
__global__ __launch_bounds__(256) void convw_kernel(
    const float* __restrict__ src, ushort_t* __restrict__ dst)
{
  const int idx = blockIdx.x * 256 + threadIdx.x;
  const int n = idx / KK, k = idx % KK;
  dst[n * KK + k] = f2bf(src[(size_t)k * NN + n]);
}

// ---------------------------------------------------------------------------
// bf16 MFMA GEMM 128x128 tile, BK=32, 4 waves (2x2), prefetch-next-K-step.
// act: 0=none,1=silu,2=gelu. obf: bf16 out else f32.
#define LDK 40

template <bool RES>
__device__ __forceinline__ void mgemm_body(
    const ushort_t* __restrict__ A, const ushort_t* __restrict__ Wt,
    const float* __restrict__ bias, const float* __restrict__ res,
    void* __restrict__ Cout, int M, int N, int K, int bx, int by,
    int act, bool obf)
{
  __shared__ ushort_t As[128 * LDK];
  __shared__ ushort_t Bs[128 * LDK];
  const int tid = threadIdx.x;
  const int wid = tid >> 6;
  const int lane = tid & 63;
  const int wm = (wid >> 1) * 64;
  const int wn = (wid & 1) * 64;
  const int m0 = by * 128, n0 = bx * 128;

  const int lrow = tid >> 1;
  const int lk   = (tid & 1) * 16;
  const int fr = lane & 15;
  const int fk = (lane >> 4) * 8;

  floatx4 acc[4][4] = {};

  uint4 av0 = *(const uint4*)&A[(size_t)(m0 + lrow) * K + lk];
  uint4 av1 = *(const uint4*)&A[(size_t)(m0 + lrow) * K + lk + 8];
  uint4 bv0 = *(const uint4*)&Wt[(size_t)(n0 + lrow) * K + lk];
  uint4 bv1 = *(const uint4*)&Wt[(size_t)(n0 + lrow) * K + lk + 8];

  for (int k0 = 0; k0 < K; k0 += 32) {
    __syncthreads();
    *(uint4*)&As[lrow * LDK + lk]     = av0;
    *(uint4*)&As[lrow * LDK + lk + 8] = av1;
    *(uint4*)&Bs[lrow * LDK + lk]     = bv0;
    *(uint4*)&Bs[lrow * LDK + lk + 8] = bv1;
    __syncthreads();
    if (k0 + 32 < K) {                 // prefetch next K-step during MFMAs
      av0 = *(const uint4*)&A[(size_t)(m0 + lrow) * K + k0 + 32 + lk];
      av1 = *(const uint4*)&A[(size_t)(m0 + lrow) * K + k0 + 32 + lk + 8];
      bv0 = *(const uint4*)&Wt[(size_t)(n0 + lrow) * K + k0 + 32 + lk];
      bv1 = *(const uint4*)&Wt[(size_t)(n0 + lrow) * K + k0 + 32 + lk + 8];
    }
    short8 af[4], bf[4];
#pragma unroll
    for (int f = 0; f < 4; f++) {
      af[f] = *(const short8*)&As[(wm + f * 16 + fr) * LDK + fk];
      bf[f] = *(const short8*)&Bs[(wn + f * 16 + fr) * LDK + fk];
    }
#pragma unroll
    for (int i = 0; i < 4; i++)
#pragma unroll
      for (int j = 0; j < 4; j++)
        acc[i][j] = __builtin_amdgcn_mfma_f32_16x16x32_bf16(af[i], bf[j], acc[i][j], 0, 0, 0);
  }

  const int g4 = (lane >> 4) * 4;
#pragma unroll
  for (int i = 0; i < 4; i++) {
#pragma unroll
    for (int j = 0; j < 4; j++) {
      const int col = n0 + wn + j * 16 + fr;
      const float bb = bias[col];
#pragma unroll
      for (int r = 0; r < 4; r++) {
        const int row = m0 + wm + i * 16 + g4 + r;
        float v = acc[i][j][r] + bb;
        if (act == 1) v = v / (1.0f + __expf(-v));
        if (act == 2) v = 0.5f * v * (1.0f + erff(v * 0.70710678118654752f));
        if (RES) v += res[(size_t)row * N + col];
        if (obf) ((ushort_t*)Cout)[(size_t)row * N + col] = f2bf(v);
        else     ((float*)Cout)[(size_t)row * N + col] = v;
      }
    }
  }
}

template <int ACT, bool RES, bool OBF>
__global__ __launch_bounds__(256) void mgemm_kernel(
    const ushort_t* __restrict__ A, const ushort_t* __restrict__ Wt,
    const float* __restrict__ bias, const float* __restrict__ res,
    void* __restrict__ C, int M, int N, int K)
{
  mgemm_body<RES>(A, Wt, bias, res, C, M, N, K, blockIdx.x, blockIdx.y, ACT, OBF);
}

// Mega-fused projections: z = 0..8 -> plane QKV (bf16 out), z = 9 -> wg1 silu (f32 out)
struct ProjArgs {
  const ushort_t* w[10];
  const float*    b[10];
  void*           c[10];
};

__global__ __launch_bounds__(256) void mgemm_proj_kernel(
    const ushort_t* __restrict__ A, ProjArgs p, int M, int N, int K)
{
  const int z = blockIdx.z;
  const int act = (z == 9) ? 1 : 0;
  const bool obf = (z != 9);
  mgemm_body<false>(A, p.w[z], p.b[z], nullptr, p.c[z], M, N, K,
                    blockIdx.x, blockIdx.y, act, obf);
}

// ---------------------------------------------------------------------------
// 64x64-tile GEMM (f32 out, +res): high-occupancy path for wo / wm2.
template <bool RES>
__global__ __launch_bounds__(256) void mgemm64_kernel(
    const ushort_t* __restrict__ A, const ushort_t* __restrict__ Wt,
    const float* __restrict__ bias, const float* __restrict__ res,
    float* __restrict__ C, int M, int N, int K)
{
  __shared__ ushort_t As[64 * LDK];
  __shared__ ushort_t Bs[64 * LDK];
  const int tid = threadIdx.x;
  const int wid = tid >> 6;
  const int lane = tid & 63;
  const int wm = (wid >> 1) * 32;
  const int wn = (wid & 1) * 32;
  const int m0 = blockIdx.y * 64, n0 = blockIdx.x * 64;

  const int lr = tid >> 2;
  const int lq = (tid & 3) * 8;
  const int fr = lane & 15;
  const int fk = (lane >> 4) * 8;

  floatx4 acc[2][2] = {};

  uint4 av = *(const uint4*)&A[(size_t)(m0 + lr) * K + lq];
  uint4 bv = *(const uint4*)&Wt[(size_t)(n0 + lr) * K + lq];

  for (int k0 = 0; k0 < K; k0 += 32) {
    __syncthreads();
    *(uint4*)&As[lr * LDK + lq] = av;
    *(uint4*)&Bs[lr * LDK + lq] = bv;
    __syncthreads();
    if (k0 + 32 < K) {
      av = *(const uint4*)&A[(size_t)(m0 + lr) * K + k0 + 32 + lq];
      bv = *(const uint4*)&Wt[(size_t)(n0 + lr) * K + k0 + 32 + lq];
    }
    short8 af[2], bf[2];
#pragma unroll
    for (int f = 0; f < 2; f++) {
      af[f] = *(const short8*)&As[(wm + f * 16 + fr) * LDK + fk];
      bf[f] = *(const short8*)&Bs[(wn + f * 16 + fr) * LDK + fk];
    }
#pragma unroll
    for (int i = 0; i < 2; i++)
#pragma unroll
      for (int j = 0; j < 2; j++)
        acc[i][j] = __builtin_amdgcn_mfma_f32_16x16x32_bf16(af[i], bf[j], acc[i][j], 0, 0, 0);
  }

  const int g4 = (lane >> 4) * 4;
#pragma unroll
  for (int i = 0; i < 2; i++) {
#pragma unroll
    for (int j = 0; j < 2; j++) {
      const int col = n0 + wn + j * 16 + fr;
      const float bb = bias[col];
#pragma unroll
      for (int r = 0; r < 4; r++) {
        const int row = m0 + wm + i * 16 + g4 + r;
        float v = acc[i][j][r] + bb;
        if (RES) v += res[(size_t)row * N + col];
        C[(size_t)row * N + col] = v;
      }
    }
  }
}

// ---------------------------------------------------------------------------
// token index for (plane, plane-batch bb, plane-seq s) -> flat token
__device__ __forceinline__ int tok_map_rt(int plane, int bb, int s) {
  if (plane == 0) return bb * 256 + s;
  if (plane == 1) return (bb >> 4) * 8192 + (s >> 4) * 256 + (s & 15) * 16 + (bb & 15);
  return (bb >> 4) * 8192 + (s >> 4) * 256 + (bb & 15) * 16 + (s & 15);
}

// ---------------------------------------------------------------------------
// Fused MFMA flash attention, all 3 planes in one dispatch.
// grid = (NHD, 768): y>>8 = plane; plane 0: qc=r>>6, bb=r&63 (S=256, non-causal);
// planes 1,2: qc=r>>5, bb=r&31 (S=512, block-causal 16).
// 4 waves x 16 q-rows. LDS XOR-swizzle (block b' = b ^ (row>>2), stride 72)
// makes Pls/Vt writes conflict-free and b128 reads ~2-way.
__global__ __launch_bounds__(256) void mattn_all_kernel(
    const ushort_t* __restrict__ qkv, float* __restrict__ ohw,
    float* __restrict__ oht, float* __restrict__ owt)
{
  __shared__ ushort_t Kls[64 * 40];       // [key][dim] 5120 B
  __shared__ ushort_t Vt[32 * 72];        // [dim][key-swz] 4608 B
  __shared__ ushort_t Pls[4 * 16 * 72];   // per-wave [qrow][key-swz] 9216 B

  const int head = blockIdx.x;
  const int yy = blockIdx.y;
  const int plane = yy >> 8;
  const int rm = yy & 255;
  int qc, bb, S;
  bool causal;
  if (plane == 0) { qc = rm >> 6; bb = rm & 63; S = 256; causal = false; }
  else            { qc = rm >> 5; bb = rm & 31; S = 512; causal = true;  }

  const size_t NDU = (size_t)NTOK * DD;
  const ushort_t* Qg = qkv + (size_t)(plane * 3 + 0) * NDU;
  const ushort_t* Kg = qkv + (size_t)(plane * 3 + 1) * NDU;
  const ushort_t* Vg = qkv + (size_t)(plane * 3 + 2) * NDU;
  float* Og = (plane == 0) ? ohw : (plane == 1) ? oht : owt;

  const int tid = threadIdx.x;
  const int wid = tid >> 6;
  const int lane = tid & 63;
  const int fr = lane & 15;
  const int hi = lane >> 4;
  const float scale = 0.17677669529663687f;

  const int q0 = qc * 64;

  const int qtok_a = tok_map_rt(plane, bb, q0 + wid * 16 + fr);
  const short8 qfrag = *(const short8*)&Qg[(size_t)qtok_a * DD + head * DHD + hi * 8];

  floatx4 o0 = {}, o1 = {};
  float mrun[4] = {-3e30f, -3e30f, -3e30f, -3e30f};
  float lrun[4] = {0.f, 0.f, 0.f, 0.f};

  const int lim = causal ? (q0 + wid * 16 + 16) : S;  // wave-uniform
  const int ntiles = (causal ? (q0 + 64) : S) >> 6;   // block-uniform

  const int krow = tid >> 2;
  const int g    = tid & 3;
  const int kseg = g * 8;

  // prefetch tile 0
  int ptok = tok_map_rt(plane, bb, krow);
  uint4 kv = *(const uint4*)&Kg[(size_t)ptok * DD + head * DHD + kseg];
  uint4 vv = *(const uint4*)&Vg[(size_t)ptok * DD + head * DHD + kseg];

  for (int t = 0; t < ntiles; t++) {
    __syncthreads();                     // previous tile's readers done
    *(uint4*)&Kls[krow * 40 + kseg] = kv;
    {
      const ushort_t* vp = (const ushort_t*)&vv;
#pragma unroll
      for (int d = 0; d < 8; d++) {
        const int dim = kseg + d;
        Vt[dim * 72 + (((krow >> 3) ^ (dim >> 2)) << 3) + (krow & 7)] = vp[d];
      }
    }
    __syncthreads();
    if (t + 1 < ntiles) {                // prefetch next tile during compute
      ptok = tok_map_rt(plane, bb, (t + 1) * 64 + krow);
      kv = *(const uint4*)&Kg[(size_t)ptok * DD + head * DHD + kseg];
      vv = *(const uint4*)&Vg[(size_t)ptok * DD + head * DHD + kseg];
    }

    const int kt0 = t * 64;
    if (causal && kt0 >= lim) continue;  // wave-uniform skip
    const int kend = causal ? min(lim - kt0, 64) : 64;

    // ---- QK^T
    floatx4 sacc[4];
#pragma unroll
    for (int j = 0; j < 4; j++) {
      floatx4 z = {};
      const short8 kf = *(const short8*)&Kls[(j * 16 + fr) * 40 + hi * 8];
      sacc[j] = __builtin_amdgcn_mfma_f32_16x16x32_bf16(qfrag, kf, z, 0, 0, 0);
    }

    float sc[4][4];
    float mt[4] = {-3e30f, -3e30f, -3e30f, -3e30f};
#pragma unroll
    for (int j = 0; j < 4; j++) {
      const bool valid = !causal || (j * 16 + fr) < kend;
#pragma unroll
      for (int r = 0; r < 4; r++) {
        const float sv = valid ? sacc[j][r] * scale : -3e30f;
        sc[j][r] = sv;
        mt[r] = fmaxf(mt[r], sv);
      }
    }
#pragma unroll
    for (int r = 0; r < 4; r++) {
      mt[r] = fmaxf(mt[r], __shfl_xor(mt[r], 1, 64));
      mt[r] = fmaxf(mt[r], __shfl_xor(mt[r], 2, 64));
      mt[r] = fmaxf(mt[r], __shfl_xor(mt[r], 4, 64));
      mt[r] = fmaxf(mt[r], __shfl_xor(mt[r], 8, 64));
    }

    float corr[4], psum[4];
#pragma unroll
    for (int r = 0; r < 4; r++) {
      const float mnew = fmaxf(mrun[r], mt[r]);
      corr[r] = __expf(mrun[r] - mnew);
      mrun[r] = mnew;
      psum[r] = 0.f;
    }

    // ---- P -> bf16 -> Pls (swizzled: block (2j+(fr>>3))^hi), psum of rounded p
    const int pbase = wid * (16 * 72);
#pragma unroll
    for (int j = 0; j < 4; j++) {
#pragma unroll
      for (int r = 0; r < 4; r++) {
        const float p = __expf(sc[j][r] - mrun[r]);
        const ushort_t pb = f2bf(p);
        psum[r] += __uint_as_float((unsigned)pb << 16);
        Pls[pbase + (hi * 4 + r) * 72 + (((2 * j + (fr >> 3)) ^ hi) << 3) + (fr & 7)] = pb;
      }
    }
#pragma unroll
    for (int r = 0; r < 4; r++) {
      psum[r] += __shfl_xor(psum[r], 1, 64);
      psum[r] += __shfl_xor(psum[r], 2, 64);
      psum[r] += __shfl_xor(psum[r], 4, 64);
      psum[r] += __shfl_xor(psum[r], 8, 64);
      lrun[r] = lrun[r] * corr[r] + psum[r];
      o0[r] *= corr[r];
      o1[r] *= corr[r];
    }

    // ---- PV
#pragma unroll
    for (int kh = 0; kh < 2; kh++) {
      const int bq = (hi + 4 * kh);
      const short8 pa  = *(const short8*)&Pls[pbase + fr * 72 + ((bq ^ (fr >> 2)) << 3)];
      const short8 vb0 = *(const short8*)&Vt[fr * 72 + ((bq ^ (fr >> 2)) << 3)];
      const short8 vb1 = *(const short8*)&Vt[(16 + fr) * 72 + ((bq ^ ((fr >> 2) + 4)) << 3)];
      o0 = __builtin_amdgcn_mfma_f32_16x16x32_bf16(pa, vb0, o0, 0, 0, 0);
      o1 = __builtin_amdgcn_mfma_f32_16x16x32_bf16(pa, vb1, o1, 0, 0, 0);
    }
  }

  // ---- epilogue
#pragma unroll
  for (int r = 0; r < 4; r++) {
    const float inv = 1.0f / lrun[r];
    const int otok = tok_map_rt(plane, bb, q0 + wid * 16 + hi * 4 + r);
    float* ob = &Og[(size_t)otok * DD + head * DHD];
    ob[fr] = o0[r] * inv;
    ob[16 + fr] = o1[r] * inv;
  }
}

// ---------------------------------------------------------------------------
// gate logits + softmax over 3 (t is f32)
__global__ __launch_bounds__(256) void gate_kernel(
    const float* __restrict__ t, const float* __restrict__ wg2,
    const float* __restrict__ bg2, float* __restrict__ gates)
{
  const int idx = blockIdx.x * 256 + threadIdx.x;
  const int token = idx >> 3, head = idx & 7;
  float a0 = bg2[head * 3 + 0], a1 = bg2[head * 3 + 1], a2 = bg2[head * 3 + 2];
  const float* trow = &t[(size_t)token * DD];
  const float* wbase = &wg2[head * 3];
  for (int k4 = 0; k4 < 64; k4++) {
    const float4 tv = *(const float4*)&trow[k4 * 4];
    const float* wr = &wbase[(k4 * 4) * 24];
    a0 = fmaf(tv.x, wr[0],      a0); a1 = fmaf(tv.x, wr[1],      a1); a2 = fmaf(tv.x, wr[2],      a2);
    a0 = fmaf(tv.y, wr[24 + 0], a0); a1 = fmaf(tv.y, wr[24 + 1], a1); a2 = fmaf(tv.y, wr[24 + 2], a2);
    a0 = fmaf(tv.z, wr[48 + 0], a0); a1 = fmaf(tv.z, wr[48 + 1], a1); a2 = fmaf(tv.z, wr[48 + 2], a2);
    a0 = fmaf(tv.w, wr[72 + 0], a0); a1 = fmaf(tv.w, wr[72 + 1], a1); a2 = fmaf(tv.w, wr[72 + 2], a2);
  }
  const float mx = fmaxf(a0, fmaxf(a1, a2));
  const float e0 = __expf(a0 - mx), e1 = __expf(a1 - mx), e2 = __expf(a2 - mx);
  const float inv = 1.0f / (e0 + e1 + e2);
  float* gp = &gates[(size_t)token * 24 + head * 3];
  gp[0] = e0 * inv; gp[1] = e1 * inv; gp[2] = e2 * inv;
}

// ---------------------------------------------------------------------------
// m = g0*o_hw + g1*o_ht + g2*o_wt -> bf16
__global__ __launch_bounds__(256) void combine_kernel(
    const float* __restrict__ gates, const float* __restrict__ ohw,
    const float* __restrict__ oht, const float* __restrict__ owt,
    ushort_t* __restrict__ m)
{
  const int idx = blockIdx.x * 256 + threadIdx.x;
  const int token = idx >> 6;
  const int head = (idx >> 3) & 7;
  const float* gp = &gates[(size_t)token * 24 + head * 3];
  const float g0 = gp[0], g1 = gp[1], g2 = gp[2];
  const float4 a = ((const float4*)ohw)[idx];
  const float4 b = ((const float4*)oht)[idx];
  const float4 c = ((const float4*)owt)[idx];
  ushort4 r;
  r.x = f2bf(g0 * a.x + g1 * b.x + g2 * c.x);
  r.y = f2bf(g0 * a.y + g1 * b.y + g2 * c.y);
  r.z = f2bf(g0 * a.z + g1 * b.z + g2 * c.z);
  r.w = f2bf(g0 * a.w + g1 * b.w + g2 * c.w);
  ((ushort4*)m)[idx] = r;
}

// ---------------------------------------------------------------------------
extern "C" void kernel_launch(void* const* d_in, const int* in_sizes, int n_in,
                              void* d_out, int out_size, void* d_ws, size_t ws_size,
                              hipStream_t stream)
{
  (void)in_sizes; (void)n_in; (void)out_size; (void)ws_size;
  const float* x   = (const float*)d_in[0];
  const float* g1  = (const float*)d_in[1];
  const float* b1  = (const float*)d_in[2];
  const float* wq[3] = {(const float*)d_in[3], (const float*)d_in[9],  (const float*)d_in[15]};
  const float* bq[3] = {(const float*)d_in[4], (const float*)d_in[10], (const float*)d_in[16]};
  const float* wk[3] = {(const float*)d_in[5], (const float*)d_in[11], (const float*)d_in[17]};
  const float* bk[3] = {(const float*)d_in[6], (const float*)d_in[12], (const float*)d_in[18]};
  const float* wv[3] = {(const float*)d_in[7], (const float*)d_in[13], (const float*)d_in[19]};
  const float* bv[3] = {(const float*)d_in[8], (const float*)d_in[14], (const float*)d_in[20]};
  const float* wo  = (const float*)d_in[21];
  const float* bo  = (const float*)d_in[22];
  const float* wg1 = (const float*)d_in[23];
  const float* bg1 = (const float*)d_in[24];
  const float* wg2 = (const float*)d_in[25];
  const float* bg2 = (const float*)d_in[26];
  const float* g2  = (const float*)d_in[27];
  const float* b2  = (const float*)d_in[28];
  const float* wm1 = (const float*)d_in[29];
  const float* bm1 = (const float*)d_in[30];
  const float* wm2 = (const float*)d_in[31];
  const float* bm2 = (const float*)d_in[32];

  const size_t NDU = (size_t)NTOK * DD;   // 4,194,304 elements

  // workspace layout
  ushort_t* U = (ushort_t*)d_ws;
  ushort_t* Ybf  = U;                     // NDU bf16
  ushort_t* Y2bf = U + NDU;               // NDU bf16
  ushort_t* qkvb = U + 2 * NDU;           // 9 * NDU bf16 (plane-major q,k,v)
  ushort_t* Mbf  = U + 11 * NDU;          // NDU bf16
  float* F   = (float*)(U + 12 * NDU);
  float* Ohw = F;                         // NDU f32
  float* Oht = Ohw + NDU;
  float* Owt = Oht + NDU;
  float* TX  = Owt + NDU;                 // NDU f32: Ts (wg1 silu out), then X1
  float* Gt  = TX + NDU;                  // NTOK*24
  ushort_t* Wbf = (ushort_t*)(Gt + (size_t)NTOK * 24);
  ushort_t* wbf11[11];
  for (int i = 0; i < 11; i++) wbf11[i] = Wbf + (size_t)i * 65536;
  ushort_t* wm1bf = Wbf + (size_t)11 * 65536;
  ushort_t* wm2bf = wm1bf + 262144;
  ushort_t* Hh = qkvb;                    // MLP hidden bf16 (aliases dead qkv)

  const dim3 blk(256);

  // 0. weight convert+transpose
  {
    W11 p;
    const float* srcs[11] = {wq[0], wk[0], wv[0], wq[1], wk[1], wv[1],
                             wq[2], wk[2], wv[2], wg1, wo};
    for (int i = 0; i < 11; i++) { p.s[i] = srcs[i]; p.d[i] = wbf11[i]; }
    convw11_kernel<<<dim3(256, 11), blk, 0, stream>>>(p);
    convw_kernel<256, 1024><<<1024, blk, 0, stream>>>(wm1, wm1bf);
    convw_kernel<1024, 256><<<1024, blk, 0, stream>>>(wm2, wm2bf);
  }

  // 1. y = LN(x) -> bf16
  ln_bf_kernel<<<NTOK / 4, blk, 0, stream>>>(x, g1, b1, Ybf);

  // 2. mega-fused projections: 9x QKV (bf16) + wg1 silu (f32 -> TX)
  {
    ProjArgs p;
    for (int pl = 0; pl < 3; pl++) {
      p.w[pl * 3 + 0] = wbf11[pl * 3 + 0]; p.b[pl * 3 + 0] = bq[pl];
      p.w[pl * 3 + 1] = wbf11[pl * 3 + 1]; p.b[pl * 3 + 1] = bk[pl];
      p.w[pl * 3 + 2] = wbf11[pl * 3 + 2]; p.b[pl * 3 + 2] = bv[pl];
      for (int wch = 0; wch < 3; wch++)
        p.c[pl * 3 + wch] = qkvb + (size_t)(pl * 3 + wch) * NDU;
    }
    p.w[9] = wbf11[9]; p.b[9] = bg1; p.c[9] = TX;
    mgemm_proj_kernel<<<dim3(2, 128, 10), blk, 0, stream>>>(Ybf, p, NTOK, DD, DD);
  }

  // 3. gates = softmax3(silu_t @ wg2 + bg2)
  gate_kernel<<<NTOK * NHD / 256, blk, 0, stream>>>(TX, wg2, bg2, Gt);

  // 4. fused attention, all 3 planes (grid y: 256 HW + 256 HT + 256 WT)
  mattn_all_kernel<<<dim3(NHD, 768), blk, 0, stream>>>(qkvb, Ohw, Oht, Owt);

  // 5. m = gated combine -> bf16
  combine_kernel<<<NTOK * 64 / 256, blk, 0, stream>>>(Gt, Ohw, Oht, Owt, Mbf);

  // 6. x1 = x + m@wo + bo (f32 -> TX)
  mgemm64_kernel<true><<<dim3(4, 256), blk, 0, stream>>>(Mbf, wbf11[10], bo, x, TX, NTOK, DD, DD);

  // 7. y2 = LN(x1) -> bf16
  ln_bf_kernel<<<NTOK / 4, blk, 0, stream>>>(TX, g2, b2, Y2bf);

  // 8. h = gelu(y2@wm1+bm1) -> bf16
  mgemm_kernel<2, false, true><<<dim3(8, 128), blk, 0, stream>>>(Y2bf, wm1bf, bm1, nullptr, Hh, NTOK, 1024, DD);

  // 9. out = x1 + h@wm2 + bm2 (f32)
  mgemm64_kernel<true><<<dim3(4, 256), blk, 0, stream>>>(Hh, wm2bf, bm2, TX, (float*)d_out, NTOK, DD, 1024);
}

// Round 8
// 346.129 us; speedup vs baseline: 4.2364x; 1.1177x over previous
//
#include <hip/hip_runtime.h>
#include <math.h>

// Problem constants: B=2, T=32, H=16, W=16, D=256, NH=8, DH=32
#define NTOK 16384
#define DD   256
#define NHD  8
#define DHD  32

typedef unsigned short ushort_t;
using short8  = __attribute__((ext_vector_type(8))) short;
using floatx4 = __attribute__((ext_vector_type(4))) float;

__device__ __forceinline__ ushort_t f2bf(float f) {
  unsigned u = __float_as_uint(f);
  u = (u + 0x7FFFu + ((u >> 16) & 1u)) >> 16;
  return (ushort_t)u;
}

__device__ __forceinline__ float wave_sum(float v) {
#pragma unroll
  for (int off = 32; off; off >>= 1) v += __shfl_xor(v, off, 64);
  return v;
}

// ---------------------------------------------------------------------------
// LayerNorm over D=256 -> bf16
__global__ __launch_bounds__(256) void ln_bf_kernel(
    const float* __restrict__ x, const float* __restrict__ g,
    const float* __restrict__ b, ushort_t* __restrict__ y)
{
  const int row  = blockIdx.x * 4 + (threadIdx.x >> 6);
  const int lane = threadIdx.x & 63;
  const float4 xv = *(const float4*)&x[(size_t)row * DD + lane * 4];
  float s = xv.x + xv.y + xv.z + xv.w;
  s = wave_sum(s);
  const float mu = s * (1.0f / DD);
  const float dx = xv.x - mu, dy = xv.y - mu, dz = xv.z - mu, dw = xv.w - mu;
  float ss = dx * dx + dy * dy + dz * dz + dw * dw;
  ss = wave_sum(ss);
  const float rs = rsqrtf(ss * (1.0f / DD) + 1e-5f);
  const float4 gv = *(const float4*)&g[lane * 4];
  const float4 bv = *(const float4*)&b[lane * 4];
  ushort4 o;
  o.x = f2bf(dx * rs * gv.x + bv.x);
  o.y = f2bf(dy * rs * gv.y + bv.y);
  o.z = f2bf(dz * rs * gv.z + bv.z);
  o.w = f2bf(dw * rs * gv.w + bv.w);
  *(ushort4*)&y[(size_t)row * DD + lane * 4] = o;
}

// ---------------------------------------------------------------------------
// Unified LDS-tiled weight transpose+convert: 19 entries of 256x256 blocks.
// src f32 [.][ss], dst bf16 [.][ds]; dst[n][k] = src[k][n]. Coalesced both sides.
struct TT { const float* s[19]; ushort_t* d[19]; int ss[19]; int ds[19]; };

__global__ __launch_bounds__(256) void convt_kernel(TT p) {
  __shared__ ushort_t t[64][65];
  const int e = blockIdx.y;
  const float* src = p.s[e];
  ushort_t* dst = p.d[e];
  const int ss = p.ss[e], ds = p.ds[e];
  const int tr = (blockIdx.x & 3) * 64;
  const int tc = (blockIdx.x >> 2) * 64;
  const int lr = threadIdx.x >> 6;
  const int lc = threadIdx.x & 63;
#pragma unroll
  for (int i = 0; i < 16; i++) {
    const int r = i * 4 + lr;
    t[r][lc] = f2bf(src[(size_t)(tr + r) * ss + tc + lc]);
  }
  __syncthreads();
#pragma unroll
  for (int i = 0; i < 16; i++) {
    const int r = i * 4 + lr;
    dst[(size_t)(tc + r) * ds + tr + lc] = t[lc][r];
  }
}

// ---------------------------------------------------------------------------
// bf16 MFMA GEMM 128x128 tile, BK=32, 4 waves (2x2), prefetch-next-K-step.
#define LDK 40

template <bool RES>
__device__ __forceinline__ void mgemm_body(
    const ushort_t* __restrict__ A, const ushort_t* __restrict__ Wt,
    const float* __restrict__ bias, const float* __restrict__ res,
    void* __restrict__ Cout, int M, int N, int K, int bx, int by,
    int act, bool obf, float oscale)
{
  __shared__ ushort_t As[128 * LDK];
  __shared__ ushort_t Bs[128 * LDK];
  const int tid = threadIdx.x;
  const int wid = tid >> 6;
  const int lane = tid & 63;
  const int wm = (wid >> 1) * 64;
  const int wn = (wid & 1) * 64;
  const int m0 = by * 128, n0 = bx * 128;

  const int lrow = tid >> 1;
  const int lk   = (tid & 1) * 16;
  const int fr = lane & 15;
  const int fk = (lane >> 4) * 8;

  floatx4 acc[4][4] = {};

  uint4 av0 = *(const uint4*)&A[(size_t)(m0 + lrow) * K + lk];
  uint4 av1 = *(const uint4*)&A[(size_t)(m0 + lrow) * K + lk + 8];
  uint4 bv0 = *(const uint4*)&Wt[(size_t)(n0 + lrow) * K + lk];
  uint4 bv1 = *(const uint4*)&Wt[(size_t)(n0 + lrow) * K + lk + 8];

  for (int k0 = 0; k0 < K; k0 += 32) {
    __syncthreads();
    *(uint4*)&As[lrow * LDK + lk]     = av0;
    *(uint4*)&As[lrow * LDK + lk + 8] = av1;
    *(uint4*)&Bs[lrow * LDK + lk]     = bv0;
    *(uint4*)&Bs[lrow * LDK + lk + 8] = bv1;
    __syncthreads();
    if (k0 + 32 < K) {
      av0 = *(const uint4*)&A[(size_t)(m0 + lrow) * K + k0 + 32 + lk];
      av1 = *(const uint4*)&A[(size_t)(m0 + lrow) * K + k0 + 32 + lk + 8];
      bv0 = *(const uint4*)&Wt[(size_t)(n0 + lrow) * K + k0 + 32 + lk];
      bv1 = *(const uint4*)&Wt[(size_t)(n0 + lrow) * K + k0 + 32 + lk + 8];
    }
    short8 af[4], bf[4];
#pragma unroll
    for (int f = 0; f < 4; f++) {
      af[f] = *(const short8*)&As[(wm + f * 16 + fr) * LDK + fk];
      bf[f] = *(const short8*)&Bs[(wn + f * 16 + fr) * LDK + fk];
    }
#pragma unroll
    for (int i = 0; i < 4; i++)
#pragma unroll
      for (int j = 0; j < 4; j++)
        acc[i][j] = __builtin_amdgcn_mfma_f32_16x16x32_bf16(af[i], bf[j], acc[i][j], 0, 0, 0);
  }

  const int g4 = (lane >> 4) * 4;
#pragma unroll
  for (int i = 0; i < 4; i++) {
#pragma unroll
    for (int j = 0; j < 4; j++) {
      const int col = n0 + wn + j * 16 + fr;
      const float bb = bias[col];
#pragma unroll
      for (int r = 0; r < 4; r++) {
        const int row = m0 + wm + i * 16 + g4 + r;
        float v = acc[i][j][r] + bb;
        if (act == 1) v = v / (1.0f + __expf(-v));
        if (act == 2) v = 0.5f * v * (1.0f + erff(v * 0.70710678118654752f));
        v *= oscale;
        if (RES) v += res[(size_t)row * N + col];
        if (obf) ((ushort_t*)Cout)[(size_t)row * N + col] = f2bf(v);
        else     ((float*)Cout)[(size_t)row * N + col] = v;
      }
    }
  }
}

template <int ACT, bool RES, bool OBF>
__global__ __launch_bounds__(256) void mgemm_kernel(
    const ushort_t* __restrict__ A, const ushort_t* __restrict__ Wt,
    const float* __restrict__ bias, const float* __restrict__ res,
    void* __restrict__ C, int M, int N, int K)
{
  mgemm_body<RES>(A, Wt, bias, res, C, M, N, K, blockIdx.x, blockIdx.y, ACT, OBF, 1.0f);
}

// Mega-fused projections: z=0..8 plane QKV (bf16; Q pre-scaled by 1/sqrt(DH)),
// z=9 -> wg1 silu (f32 out)
struct ProjArgs {
  const ushort_t* w[10];
  const float*    b[10];
  void*           c[10];
};

__global__ __launch_bounds__(256) void mgemm_proj_kernel(
    const ushort_t* __restrict__ A, ProjArgs p, int M, int N, int K)
{
  const int z = blockIdx.z;
  const int act = (z == 9) ? 1 : 0;
  const bool obf = (z != 9);
  const float osc = (z < 9 && (z % 3) == 0) ? 0.17677669529663687f : 1.0f;
  mgemm_body<false>(A, p.w[z], p.b[z], nullptr, p.c[z], M, N, K,
                    blockIdx.x, blockIdx.y, act, obf, osc);
}

// ---------------------------------------------------------------------------
// 64x64-tile GEMM (f32 out, +res): high-occupancy path for wo / wm2.
template <bool RES>
__global__ __launch_bounds__(256) void mgemm64_kernel(
    const ushort_t* __restrict__ A, const ushort_t* __restrict__ Wt,
    const float* __restrict__ bias, const float* __restrict__ res,
    float* __restrict__ C, int M, int N, int K)
{
  __shared__ ushort_t As[64 * LDK];
  __shared__ ushort_t Bs[64 * LDK];
  const int tid = threadIdx.x;
  const int wid = tid >> 6;
  const int lane = tid & 63;
  const int wm = (wid >> 1) * 32;
  const int wn = (wid & 1) * 32;
  const int m0 = blockIdx.y * 64, n0 = blockIdx.x * 64;

  const int lr = tid >> 2;
  const int lq = (tid & 3) * 8;
  const int fr = lane & 15;
  const int fk = (lane >> 4) * 8;

  floatx4 acc[2][2] = {};

  uint4 av = *(const uint4*)&A[(size_t)(m0 + lr) * K + lq];
  uint4 bv = *(const uint4*)&Wt[(size_t)(n0 + lr) * K + lq];

  for (int k0 = 0; k0 < K; k0 += 32) {
    __syncthreads();
    *(uint4*)&As[lr * LDK + lq] = av;
    *(uint4*)&Bs[lr * LDK + lq] = bv;
    __syncthreads();
    if (k0 + 32 < K) {
      av = *(const uint4*)&A[(size_t)(m0 + lr) * K + k0 + 32 + lq];
      bv = *(const uint4*)&Wt[(size_t)(n0 + lr) * K + k0 + 32 + lq];
    }
    short8 af[2], bf[2];
#pragma unroll
    for (int f = 0; f < 2; f++) {
      af[f] = *(const short8*)&As[(wm + f * 16 + fr) * LDK + fk];
      bf[f] = *(const short8*)&Bs[(wn + f * 16 + fr) * LDK + fk];
    }
#pragma unroll
    for (int i = 0; i < 2; i++)
#pragma unroll
      for (int j = 0; j < 2; j++)
        acc[i][j] = __builtin_amdgcn_mfma_f32_16x16x32_bf16(af[i], bf[j], acc[i][j], 0, 0, 0);
  }

  const int g4 = (lane >> 4) * 4;
#pragma unroll
  for (int i = 0; i < 2; i++) {
#pragma unroll
    for (int j = 0; j < 2; j++) {
      const int col = n0 + wn + j * 16 + fr;
      const float bb = bias[col];
#pragma unroll
      for (int r = 0; r < 4; r++) {
        const int row = m0 + wm + i * 16 + g4 + r;
        float v = acc[i][j][r] + bb;
        if (RES) v += res[(size_t)row * N + col];
        C[(size_t)row * N + col] = v;
      }
    }
  }
}

// ---------------------------------------------------------------------------
// token index for (plane, plane-batch bb, plane-seq s) -> flat token
__device__ __forceinline__ int tok_map_rt(int plane, int bb, int s) {
  if (plane == 0) return bb * 256 + s;
  if (plane == 1) return (bb >> 4) * 8192 + (s >> 4) * 256 + (s & 15) * 16 + (bb & 15);
  return (bb >> 4) * 8192 + (s >> 4) * 256 + (bb & 15) * 16 + (s & 15);
}

// ---------------------------------------------------------------------------
// Fused MFMA flash attention, all 3 planes, SWAPPED QK^T (S^T = K*Q^T):
// lane (fr,hi) holds the P-row slice for q=fr, keys j*16+hi*4+{0..3} -> row
// softmax is 2 shuffles; causal masking = whole-j-tile skip (kend % 16 == 0);
// P packs via v_cvt_pk_bf16_f32 into b32 LDS stores (A-frag layout), PV reads
// b128. Q arrives pre-scaled by 1/sqrt(DH) from the projection.
__global__ __launch_bounds__(256) void mattn_all_kernel(
    const ushort_t* __restrict__ qkv, float* __restrict__ ohw,
    float* __restrict__ oht, float* __restrict__ owt)
{
  __shared__ ushort_t Kls[64 * 40];       // [key][dim] 5120 B
  __shared__ ushort_t Vt[32 * 72];        // [dim][key-swz] 4608 B
  __shared__ unsigned PlsU[4][16 * 36];   // per-wave [q=fr][packed key-pairs] 9216 B

  const int head = blockIdx.x;
  const int yy = blockIdx.y;
  const int plane = yy >> 8;
  const int rm = yy & 255;
  int qc, bb, S;
  bool causal;
  if (plane == 0) { qc = rm >> 6; bb = rm & 63; S = 256; causal = false; }
  else            { qc = rm >> 5; bb = rm & 31; S = 512; causal = true;  }

  const size_t NDU = (size_t)NTOK * DD;
  const ushort_t* Qg = qkv + (size_t)(plane * 3 + 0) * NDU;
  const ushort_t* Kg = qkv + (size_t)(plane * 3 + 1) * NDU;
  const ushort_t* Vg = qkv + (size_t)(plane * 3 + 2) * NDU;
  float* Og = (plane == 0) ? ohw : (plane == 1) ? oht : owt;

  const int tid = threadIdx.x;
  const int wid = tid >> 6;
  const int lane = tid & 63;
  const int fr = lane & 15;
  const int hi = lane >> 4;

  const int q0 = qc * 64;

  const int qtok_a = tok_map_rt(plane, bb, q0 + wid * 16 + fr);
  const short8 qfrag = *(const short8*)&Qg[(size_t)qtok_a * DD + head * DHD + hi * 8];

  floatx4 o0 = {}, o1 = {};
  float mrun = -3e30f, lrun = 0.0f;       // state for q-row = fr

  const int lim = causal ? (q0 + wid * 16 + 16) : S;  // wave-uniform
  const int ntiles = (causal ? (q0 + 64) : S) >> 6;

  const int krow = tid >> 2;
  const int g    = tid & 3;
  const int kseg = g * 8;

  // prefetch tile 0
  int ptok = tok_map_rt(plane, bb, krow);
  uint4 kv = *(const uint4*)&Kg[(size_t)ptok * DD + head * DHD + kseg];
  uint4 vv = *(const uint4*)&Vg[(size_t)ptok * DD + head * DHD + kseg];

  for (int t = 0; t < ntiles; t++) {
    __syncthreads();
    *(uint4*)&Kls[krow * 40 + kseg] = kv;
    {
      const ushort_t* vp = (const ushort_t*)&vv;
#pragma unroll
      for (int d = 0; d < 8; d++) {
        const int dim = kseg + d;
        Vt[dim * 72 + (((krow >> 3) ^ (dim >> 2)) << 3) + (krow & 7)] = vp[d];
      }
    }
    __syncthreads();
    if (t + 1 < ntiles) {
      ptok = tok_map_rt(plane, bb, (t + 1) * 64 + krow);
      kv = *(const uint4*)&Kg[(size_t)ptok * DD + head * DHD + kseg];
      vv = *(const uint4*)&Vg[(size_t)ptok * DD + head * DHD + kseg];
    }

    const int kt0 = t * 64;
    if (causal && kt0 >= lim) continue;                     // wave-uniform
    const int jend = causal ? (min(lim - kt0, 64) >> 4) : 4; // 1..4, wave-uniform

    // ---- QK^T swapped: sacc[j][r] = S[key=j*16+hi*4+r][q=fr]
    floatx4 sacc[4];
#pragma unroll
    for (int j = 0; j < 4; j++) {
      if (j < jend) {
        floatx4 z = {};
        const short8 kf = *(const short8*)&Kls[(j * 16 + fr) * 40 + hi * 8];
        sacc[j] = __builtin_amdgcn_mfma_f32_16x16x32_bf16(kf, qfrag, z, 0, 0, 0);
      }
    }

    // ---- row max for q=fr (local tree + 2 shuffles)
    float mt = -3e30f;
#pragma unroll
    for (int j = 0; j < 4; j++) {
      if (j < jend) {
        const float m01 = fmaxf(sacc[j][0], sacc[j][1]);
        const float m23 = fmaxf(sacc[j][2], sacc[j][3]);
        mt = fmaxf(mt, fmaxf(m01, m23));
      }
    }
    mt = fmaxf(mt, __shfl_xor(mt, 16, 64));
    mt = fmaxf(mt, __shfl_xor(mt, 32, 64));

    const float mnew = fmaxf(mrun, mt);
    const float corr = __expf(mrun - mnew);
    mrun = mnew;

    // ---- p = exp(s - m) -> packed bf16; psum from ROUNDED values
    float psum = 0.0f;
    unsigned pk[8];
#pragma unroll
    for (int j = 0; j < 4; j++) {
      if (j < jend) {
        const float p0 = __expf(sacc[j][0] - mnew);
        const float p1 = __expf(sacc[j][1] - mnew);
        const float p2 = __expf(sacc[j][2] - mnew);
        const float p3 = __expf(sacc[j][3] - mnew);
        unsigned a, b;
        asm("v_cvt_pk_bf16_f32 %0, %1, %2" : "=v"(a) : "v"(p0), "v"(p1));
        asm("v_cvt_pk_bf16_f32 %0, %1, %2" : "=v"(b) : "v"(p2), "v"(p3));
        pk[2 * j] = a; pk[2 * j + 1] = b;
        psum += __uint_as_float(a << 16) + __uint_as_float(a & 0xFFFF0000u);
        psum += __uint_as_float(b << 16) + __uint_as_float(b & 0xFFFF0000u);
      } else {
        pk[2 * j] = 0u; pk[2 * j + 1] = 0u;
      }
    }
    psum += __shfl_xor(psum, 16, 64);
    psum += __shfl_xor(psum, 32, 64);
    lrun = lrun * corr + psum;

    // ---- store packed P in A-frag layout: row q=fr, u32 idx = key_pair
    unsigned* prow = &PlsU[wid][fr * 36];
#pragma unroll
    for (int j = 0; j < 4; j++) {
      prow[j * 8 + hi * 2]     = pk[2 * j];
      prow[j * 8 + hi * 2 + 1] = pk[2 * j + 1];
    }

    // ---- rescale o: broadcast corr of q-row (hi*4+r) from lane fr'=q
#pragma unroll
    for (int r = 0; r < 4; r++) {
      const float cb = __shfl(corr, (lane & 48) + hi * 4 + r, 64);
      o0[r] *= cb;
      o1[r] *= cb;
    }

    // ---- PV (skip all-zero upper half on small diagonal tiles)
    const int khend = (jend > 2) ? 2 : 1;
#pragma unroll
    for (int kh = 0; kh < 2; kh++) {
      if (kh < khend) {
        const short8 pa = *(const short8*)&PlsU[wid][fr * 36 + kh * 16 + hi * 4];
        const int bq = hi + 4 * kh;
        const short8 vb0 = *(const short8*)&Vt[fr * 72 + ((bq ^ (fr >> 2)) << 3)];
        const short8 vb1 = *(const short8*)&Vt[(16 + fr) * 72 + ((bq ^ ((fr >> 2) + 4)) << 3)];
        o0 = __builtin_amdgcn_mfma_f32_16x16x32_bf16(pa, vb0, o0, 0, 0, 0);
        o1 = __builtin_amdgcn_mfma_f32_16x16x32_bf16(pa, vb1, o1, 0, 0, 0);
      }
    }
  }

  // ---- epilogue: broadcast 1/lrun of q-row, store f32
  const float il0 = 1.0f / lrun;
#pragma unroll
  for (int r = 0; r < 4; r++) {
    const float il = __shfl(il0, (lane & 48) + hi * 4 + r, 64);
    const int otok = tok_map_rt(plane, bb, q0 + wid * 16 + hi * 4 + r);
    float* ob = &Og[(size_t)otok * DD + head * DHD];
    ob[fr] = o0[r] * il;
    ob[16 + fr] = o1[r] * il;
  }
}

// ---------------------------------------------------------------------------
// gate logits + softmax over 3 (t is f32)
__global__ __launch_bounds__(256) void gate_kernel(
    const float* __restrict__ t, const float* __restrict__ wg2,
    const float* __restrict__ bg2, float* __restrict__ gates)
{
  const int idx = blockIdx.x * 256 + threadIdx.x;
  const int token = idx >> 3, head = idx & 7;
  float a0 = bg2[head * 3 + 0], a1 = bg2[head * 3 + 1], a2 = bg2[head * 3 + 2];
  const float* trow = &t[(size_t)token * DD];
  const float* wbase = &wg2[head * 3];
  for (int k4 = 0; k4 < 64; k4++) {
    const float4 tv = *(const float4*)&trow[k4 * 4];
    const float* wr = &wbase[(k4 * 4) * 24];
    a0 = fmaf(tv.x, wr[0],      a0); a1 = fmaf(tv.x, wr[1],      a1); a2 = fmaf(tv.x, wr[2],      a2);
    a0 = fmaf(tv.y, wr[24 + 0], a0); a1 = fmaf(tv.y, wr[24 + 1], a1); a2 = fmaf(tv.y, wr[24 + 2], a2);
    a0 = fmaf(tv.z, wr[48 + 0], a0); a1 = fmaf(tv.z, wr[48 + 1], a1); a2 = fmaf(tv.z, wr[48 + 2], a2);
    a0 = fmaf(tv.w, wr[72 + 0], a0); a1 = fmaf(tv.w, wr[72 + 1], a1); a2 = fmaf(tv.w, wr[72 + 2], a2);
  }
  const float mx = fmaxf(a0, fmaxf(a1, a2));
  const float e0 = __expf(a0 - mx), e1 = __expf(a1 - mx), e2 = __expf(a2 - mx);
  const float inv = 1.0f / (e0 + e1 + e2);
  float* gp = &gates[(size_t)token * 24 + head * 3];
  gp[0] = e0 * inv; gp[1] = e1 * inv; gp[2] = e2 * inv;
}

// ---------------------------------------------------------------------------
// m = g0*o_hw + g1*o_ht + g2*o_wt -> bf16
__global__ __launch_bounds__(256) void combine_kernel(
    const float* __restrict__ gates, const float* __restrict__ ohw,
    const float* __restrict__ oht, const float* __restrict__ owt,
    ushort_t* __restrict__ m)
{
  const int idx = blockIdx.x * 256 + threadIdx.x;
  const int token = idx >> 6;
  const int head = (idx >> 3) & 7;
  const float* gp = &gates[(size_t)token * 24 + head * 3];
  const float g0 = gp[0], g1 = gp[1], g2 = gp[2];
  const float4 a = ((const float4*)ohw)[idx];
  const float4 b = ((const float4*)oht)[idx];
  const float4 c = ((const float4*)owt)[idx];
  ushort4 r;
  r.x = f2bf(g0 * a.x + g1 * b.x + g2 * c.x);
  r.y = f2bf(g0 * a.y + g1 * b.y + g2 * c.y);
  r.z = f2bf(g0 * a.z + g1 * b.z + g2 * c.z);
  r.w = f2bf(g0 * a.w + g1 * b.w + g2 * c.w);
  ((ushort4*)m)[idx] = r;
}

// ---------------------------------------------------------------------------
extern "C" void kernel_launch(void* const* d_in, const int* in_sizes, int n_in,
                              void* d_out, int out_size, void* d_ws, size_t ws_size,
                              hipStream_t stream)
{
  (void)in_sizes; (void)n_in; (void)out_size; (void)ws_size;
  const float* x   = (const float*)d_in[0];
  const float* g1  = (const float*)d_in[1];
  const float* b1  = (const float*)d_in[2];
  const float* wq[3] = {(const float*)d_in[3], (const float*)d_in[9],  (const float*)d_in[15]};
  const float* bq[3] = {(const float*)d_in[4], (const float*)d_in[10], (const float*)d_in[16]};
  const float* wk[3] = {(const float*)d_in[5], (const float*)d_in[11], (const float*)d_in[17]};
  const float* bk[3] = {(const float*)d_in[6], (const float*)d_in[12], (const float*)d_in[18]};
  const float* wv[3] = {(const float*)d_in[7], (const float*)d_in[13], (const float*)d_in[19]};
  const float* bv[3] = {(const float*)d_in[8], (const float*)d_in[14], (const float*)d_in[20]};
  const float* wo  = (const float*)d_in[21];
  const float* bo  = (const float*)d_in[22];
  const float* wg1 = (const float*)d_in[23];
  const float* bg1 = (const float*)d_in[24];
  const float* wg2 = (const float*)d_in[25];
  const float* bg2 = (const float*)d_in[26];
  const float* g2  = (const float*)d_in[27];
  const float* b2  = (const float*)d_in[28];
  const float* wm1 = (const float*)d_in[29];
  const float* bm1 = (const float*)d_in[30];
  const float* wm2 = (const float*)d_in[31];
  const float* bm2 = (const float*)d_in[32];

  const size_t NDU = (size_t)NTOK * DD;   // 4,194,304 elements

  // workspace layout
  ushort_t* U = (ushort_t*)d_ws;
  ushort_t* Ybf  = U;                     // NDU bf16
  ushort_t* Y2bf = U + NDU;               // NDU bf16
  ushort_t* qkvb = U + 2 * NDU;           // 9 * NDU bf16
  ushort_t* Mbf  = U + 11 * NDU;          // NDU bf16
  float* F   = (float*)(U + 12 * NDU);
  float* Ohw = F;                         // NDU f32
  float* Oht = Ohw + NDU;
  float* Owt = Oht + NDU;
  float* TX  = Owt + NDU;                 // NDU f32: Ts (wg1 silu out), then X1
  float* Gt  = TX + NDU;                  // NTOK*24
  ushort_t* Wbf = (ushort_t*)(Gt + (size_t)NTOK * 24);
  ushort_t* wbf11[11];
  for (int i = 0; i < 11; i++) wbf11[i] = Wbf + (size_t)i * 65536;
  ushort_t* wm1bf = Wbf + (size_t)11 * 65536;
  ushort_t* wm2bf = wm1bf + 262144;
  ushort_t* Hh = qkvb;                    // MLP hidden bf16 (aliases dead qkv)

  const dim3 blk(256);

  // 0. weight convert+transpose: 19 entries of 256x256 blocks, one dispatch
  {
    TT p;
    const float* srcs[11] = {wq[0], wk[0], wv[0], wq[1], wk[1], wv[1],
                             wq[2], wk[2], wv[2], wg1, wo};
    for (int i = 0; i < 11; i++) {
      p.s[i] = srcs[i]; p.d[i] = wbf11[i]; p.ss[i] = 256; p.ds[i] = 256;
    }
    // wm1: f32 [256][1024] -> bf16 [1024][256], 4 column-chunks
    for (int i = 0; i < 4; i++) {
      p.s[11 + i] = wm1 + i * 256;
      p.d[11 + i] = wm1bf + (size_t)(i * 256) * 256;
      p.ss[11 + i] = 1024; p.ds[11 + i] = 256;
    }
    // wm2: f32 [1024][256] -> bf16 [256][1024], 4 row-chunks
    for (int i = 0; i < 4; i++) {
      p.s[15 + i] = wm2 + (size_t)(i * 256) * 256;
      p.d[15 + i] = wm2bf + i * 256;
      p.ss[15 + i] = 256; p.ds[15 + i] = 1024;
    }
    convt_kernel<<<dim3(16, 19), blk, 0, stream>>>(p);
  }

  // 1. y = LN(x) -> bf16
  ln_bf_kernel<<<NTOK / 4, blk, 0, stream>>>(x, g1, b1, Ybf);

  // 2. mega-fused projections: 9x QKV (bf16, Q pre-scaled) + wg1 silu (f32)
  {
    ProjArgs p;
    for (int pl = 0; pl < 3; pl++) {
      p.w[pl * 3 + 0] = wbf11[pl * 3 + 0]; p.b[pl * 3 + 0] = bq[pl];
      p.w[pl * 3 + 1] = wbf11[pl * 3 + 1]; p.b[pl * 3 + 1] = bk[pl];
      p.w[pl * 3 + 2] = wbf11[pl * 3 + 2]; p.b[pl * 3 + 2] = bv[pl];
      for (int wch = 0; wch < 3; wch++)
        p.c[pl * 3 + wch] = qkvb + (size_t)(pl * 3 + wch) * NDU;
    }
    p.w[9] = wbf11[9]; p.b[9] = bg1; p.c[9] = TX;
    mgemm_proj_kernel<<<dim3(2, 128, 10), blk, 0, stream>>>(Ybf, p, NTOK, DD, DD);
  }

  // 3. gates = softmax3(silu_t @ wg2 + bg2)
  gate_kernel<<<NTOK * NHD / 256, blk, 0, stream>>>(TX, wg2, bg2, Gt);

  // 4. fused attention, all 3 planes
  mattn_all_kernel<<<dim3(NHD, 768), blk, 0, stream>>>(qkvb, Ohw, Oht, Owt);

  // 5. m = gated combine -> bf16
  combine_kernel<<<NTOK * 64 / 256, blk, 0, stream>>>(Gt, Ohw, Oht, Owt, Mbf);

  // 6. x1 = x + m@wo + bo (f32 -> TX)
  mgemm64_kernel<true><<<dim3(4, 256), blk, 0, stream>>>(Mbf, wbf11[10], bo, x, TX, NTOK, DD, DD);

  // 7. y2 = LN(x1) -> bf16
  ln_bf_kernel<<<NTOK / 4, blk, 0, stream>>>(TX, g2, b2, Y2bf);

  // 8. h = gelu(y2@wm1+bm1) -> bf16
  mgemm_kernel<2, false, true><<<dim3(8, 128), blk, 0, stream>>>(Y2bf, wm1bf, bm1, nullptr, Hh, NTOK, 1024, DD);

  // 9. out = x1 + h@wm2 + bm2 (f32)
  mgemm64_kernel<true><<<dim3(4, 256), blk, 0, stream>>>(Hh, wm2bf, bm2, TX, (float*)d_out, NTOK, DD, 1024);
}